// Round 2
// baseline (466.928 us; speedup 1.0000x reference)
//
#include <hip/hip_runtime.h>
#include <hip/hip_bf16.h>

#define B_    16
#define CIN_  128
#define COUT_ 256
#define H_    80
#define W_    80
#define HO_   40
#define WO_   40
#define KK_   9
#define SK_   1152      // CIN_*KK_
#define NPIX_ 25600     // B_*HO_*WO_

// ---------------------------------------------------------------- K1: offsets
// One block per (b, ho). Stage subsampled x-row (128 ci x 40 wo) + offset
// weights in LDS, then each thread computes (o, wo) dot products.
__global__ __launch_bounds__(256) void k_offsets(const float* __restrict__ x,
                                                 const float* __restrict__ ow,
                                                 const float* __restrict__ ob,
                                                 float* __restrict__ off) {
  __shared__ float xrow[CIN_ * WO_];   // 20.5 KB
  __shared__ float owl[18 * CIN_];     // 9.2 KB
  __shared__ float obl[18];
  const int tid = threadIdx.x;
  const int b  = blockIdx.x / HO_;
  const int ho = blockIdx.x % HO_;
  for (int j = tid; j < CIN_ * WO_; j += 256) {
    int ci = j / WO_, wo = j - ci * WO_;
    xrow[j] = x[((b * CIN_ + ci) * H_ + 2 * ho) * W_ + 2 * wo];
  }
  for (int j = tid; j < 18 * CIN_; j += 256) owl[j] = ow[j];
  if (tid < 18) obl[tid] = ob[tid];
  __syncthreads();
  for (int i = tid; i < 18 * WO_; i += 256) {
    int o = i / WO_, wo = i - o * WO_;
    float acc = obl[o];
    const float* wr = &owl[o * CIN_];
    const float* xr = &xrow[wo];
#pragma unroll 4
    for (int ci = 0; ci < CIN_; ci++) acc += wr[ci] * xr[ci * WO_];
    off[((b * 18 + o) * HO_ + ho) * WO_ + wo] = acc;
  }
}

// ------------------------------------------------------- KT: weight transpose
// wt[s][o] = deform_w[o][s] so phase-2 loads are coalesced float4.
__global__ __launch_bounds__(256) void k_transpose(const float* __restrict__ dw,
                                                   float* __restrict__ wt) {
  const int s = blockIdx.x;          // 0..1151
  const int o = threadIdx.x;         // 0..255
  wt[s * COUT_ + o] = dw[o * SK_ + s];
}

// -------------------------------------------- K2: fused sampling + main GEMM
// One block per (b, ho) row: 40 output pixels, all 256 output channels.
// Thread (cg = tid&63, pg = tid>>6) owns channels cg*4..cg*4+3, pixels
// pg*10..pg*10+9. Wave = one pg => smp LDS reads broadcast, wt coalesced.
__global__ __launch_bounds__(256) void k_main(const float* __restrict__ x,
                                              const float* __restrict__ off,
                                              const float* __restrict__ wt,
                                              const float* __restrict__ db,
                                              float* __restrict__ outp,
                                              float* __restrict__ accum) {
  __shared__ __align__(16) float smp[WO_ * 144];      // 23040 B  [px][sc]
  __shared__ __align__(16) int   pidx[WO_ * KK_ * 4]; // 5760 B
  __shared__ __align__(16) float pw[WO_ * KK_ * 4];   // 5760 B
  __shared__ float redS[4 * COUT_];                   // 4096 B
  __shared__ float redQ[4 * COUT_];                   // 4096 B

  const int tid = threadIdx.x;
  const int b  = blockIdx.x / HO_;
  const int ho = blockIdx.x % HO_;
  const int cg = tid & 63;
  const int pg = tid >> 6;

  // Precompute per-(px,kk): clipped corner indices + validity-masked bilinear
  // weights. sample = sum_j pw[j] * x[ci_plane][pidx[j]] afterwards.
  for (int i = tid; i < WO_ * KK_; i += 256) {
    int px = i / KK_, kk = i - px * KK_;
    float dy = off[((b * 18 + 2 * kk) * HO_ + ho) * WO_ + px];
    float dx = off[((b * 18 + 2 * kk + 1) * HO_ + ho) * WO_ + px];
    float py  = (float)(2 * ho - 1 + (kk / 3)) + dy;
    float pxf = (float)(2 * px - 1 + (kk % 3)) + dx;
    float y0f = floorf(py), x0f = floorf(pxf);
    float wy1 = py - y0f, wx1 = pxf - x0f;
    float wy0 = 1.f - wy1, wx0 = 1.f - wx1;
    int y0 = (int)y0f, x0 = (int)x0f;
    int y1 = y0 + 1, x1 = x0 + 1;
    bool vy0 = (y0 >= 0) && (y0 < H_);
    bool vy1 = (y1 >= 0) && (y1 < H_);
    bool vx0 = (x0 >= 0) && (x0 < W_);
    bool vx1 = (x1 >= 0) && (x1 < W_);
    int y0c = min(max(y0, 0), H_ - 1), y1c = min(max(y1, 0), H_ - 1);
    int x0c = min(max(x0, 0), W_ - 1), x1c = min(max(x1, 0), W_ - 1);
    pidx[i * 4 + 0] = y0c * W_ + x0c;  pw[i * 4 + 0] = (vy0 && vx0) ? wy0 * wx0 : 0.f;
    pidx[i * 4 + 1] = y0c * W_ + x1c;  pw[i * 4 + 1] = (vy0 && vx1) ? wy0 * wx1 : 0.f;
    pidx[i * 4 + 2] = y1c * W_ + x0c;  pw[i * 4 + 2] = (vy1 && vx0) ? wy1 * wx0 : 0.f;
    pidx[i * 4 + 3] = y1c * W_ + x1c;  pw[i * 4 + 3] = (vy1 && vx1) ? wy1 * wx1 : 0.f;
  }

  float acc[4][10];
#pragma unroll
  for (int cc = 0; cc < 4; cc++)
#pragma unroll
    for (int pp = 0; pp < 10; pp++) acc[cc][pp] = 0.f;

  const float* xb = x + (size_t)b * CIN_ * H_ * W_;

  // K loop: 8 chunks of 16 ci (144 samples per pixel per chunk)
  for (int ch = 0; ch < 8; ch++) {
    __syncthreads();  // smp safe to overwrite (also covers precompute on ch=0)
    const int ci0 = ch * 16;
    // phase 1: sampling into LDS
    for (int L = tid; L < WO_ * 144; L += 256) {
      int px = L / 144, sc = L - px * 144;
      int cil = sc / 9, kk = sc - cil * 9;
      const float* xp = xb + (ci0 + cil) * (H_ * W_);
      int j = (px * KK_ + kk) * 4;
      int4   I  = *(const int4*)&pidx[j];
      float4 Wv = *(const float4*)&pw[j];
      smp[L] = Wv.x * xp[I.x] + Wv.y * xp[I.y] +
               Wv.z * xp[I.z] + Wv.w * xp[I.w];
    }
    __syncthreads();
    // phase 2: register-tiled FMA over this chunk's 144 K values
    const float* wtc = wt + (ci0 * KK_) * COUT_;
    for (int sc = 0; sc < 144; sc += 4) {
      float4 w0 = *(const float4*)&wtc[(sc + 0) * COUT_ + cg * 4];
      float4 w1 = *(const float4*)&wtc[(sc + 1) * COUT_ + cg * 4];
      float4 w2 = *(const float4*)&wtc[(sc + 2) * COUT_ + cg * 4];
      float4 w3 = *(const float4*)&wtc[(sc + 3) * COUT_ + cg * 4];
#pragma unroll
      for (int pp = 0; pp < 10; pp++) {
        float4 xv = *(const float4*)&smp[(pg * 10 + pp) * 144 + sc];
        acc[0][pp] += w0.x * xv.x + w1.x * xv.y + w2.x * xv.z + w3.x * xv.w;
        acc[1][pp] += w0.y * xv.x + w1.y * xv.y + w2.y * xv.z + w3.y * xv.w;
        acc[2][pp] += w0.z * xv.x + w1.z * xv.y + w2.z * xv.z + w3.z * xv.w;
        acc[3][pp] += w0.w * xv.x + w1.w * xv.y + w2.w * xv.z + w3.w * xv.w;
      }
    }
  }

  // epilogue: bias, pre-BN store (fp32 into d_out), per-channel stats
  const int c0 = cg * 4;
#pragma unroll
  for (int cc = 0; cc < 4; cc++) {
    const int c = c0 + cc;
    float bv = db[c];
    float s1 = 0.f, s2 = 0.f;
    float* op = outp + (((size_t)b * COUT_ + c) * HO_ + ho) * WO_ + pg * 10;
#pragma unroll
    for (int pp = 0; pp < 10; pp++) {
      float v = acc[cc][pp] + bv;
      s1 += v;
      s2 += v * v;
      op[pp] = v;
    }
    redS[pg * COUT_ + c] = s1;
    redQ[pg * COUT_ + c] = s2;
  }
  __syncthreads();
  {
    const int c = tid;  // blockDim == 256 == COUT_
    float a1 = redS[c] + redS[COUT_ + c] + redS[2 * COUT_ + c] + redS[3 * COUT_ + c];
    float a2 = redQ[c] + redQ[COUT_ + c] + redQ[2 * COUT_ + c] + redQ[3 * COUT_ + c];
    atomicAdd(&accum[c], a1);
    atomicAdd(&accum[COUT_ + c], a2);
  }
}

// --------------------------------------------------- K3: BN + SiLU, in place
__global__ __launch_bounds__(256) void k_bn(float* __restrict__ io,
                                            const float* __restrict__ accum,
                                            const float* __restrict__ gamma,
                                            const float* __restrict__ beta) {
  const int t = blockIdx.x * 256 + threadIdx.x;
  const int i0 = t * 4;                       // 4 floats per thread
  const int c = (i0 / (HO_ * WO_)) % COUT_;   // 1600 % 4 == 0 -> uniform c
  const float mean = accum[c] * (1.f / NPIX_);
  const float var  = accum[COUT_ + c] * (1.f / NPIX_) - mean * mean;
  const float inv  = rsqrtf(var + 1e-5f);
  const float g  = gamma[c] * inv;
  const float be = beta[c] - mean * g;
  float4 r = *(const float4*)(io + i0);
  float v[4] = {r.x, r.y, r.z, r.w};
#pragma unroll
  for (int q = 0; q < 4; q++) {
    float u = v[q] * g + be;
    v[q] = u / (1.f + expf(-u));
  }
  *(float4*)(io + i0) = make_float4(v[0], v[1], v[2], v[3]);
}

// ----------------------------------------------------------------- launcher
extern "C" void kernel_launch(void* const* d_in, const int* in_sizes, int n_in,
                              void* d_out, int out_size, void* d_ws, size_t ws_size,
                              hipStream_t stream) {
  const float* x     = (const float*)d_in[0];
  const float* ow    = (const float*)d_in[1];
  const float* ob    = (const float*)d_in[2];
  const float* dw    = (const float*)d_in[3];
  const float* db    = (const float*)d_in[4];
  const float* gamma = (const float*)d_in[5];
  const float* beta  = (const float*)d_in[6];
  float* out = (float*)d_out;

  float* off   = (float*)d_ws;                    // 460800 floats
  float* wt    = off + B_ * 18 * HO_ * WO_;       // 294912 floats
  float* accum = wt + SK_ * COUT_;                // 512 floats

  hipMemsetAsync(accum, 0, 2 * COUT_ * sizeof(float), stream);
  k_offsets<<<B_ * HO_, 256, 0, stream>>>(x, ow, ob, off);
  k_transpose<<<SK_, 256, 0, stream>>>(dw, wt);
  k_main<<<B_ * HO_, 256, 0, stream>>>(x, off, wt, db, out, accum);
  k_bn<<<(NPIX_ * COUT_ / 4 + 255) / 256, 256, 0, stream>>>(
      out, accum, gamma, beta);
}

// Round 3
// 458.799 us; speedup vs baseline: 1.0177x; 1.0177x over previous
//
#include <hip/hip_runtime.h>
#include <hip/hip_bf16.h>

#define B_    16
#define CIN_  128
#define COUT_ 256
#define H_    80
#define W_    80
#define HO_   40
#define WO_   40
#define KK_   9
#define SK_   1152      // CIN_*KK_
#define NPIX_ 25600     // B_*HO_*WO_

typedef __attribute__((ext_vector_type(8))) short short8;
typedef __attribute__((ext_vector_type(4))) float floatx4;

__device__ __forceinline__ unsigned short f2bu(float v) {
  __hip_bfloat16 h = __float2bfloat16(v);
  return *reinterpret_cast<unsigned short*>(&h);
}

// ---------------------------------------------------------------- K1: offsets
__global__ __launch_bounds__(256) void k_offsets(const float* __restrict__ x,
                                                 const float* __restrict__ ow,
                                                 const float* __restrict__ ob,
                                                 float* __restrict__ off) {
  __shared__ float xrow[CIN_ * WO_];
  __shared__ float owl[18 * CIN_];
  __shared__ float obl[18];
  const int tid = threadIdx.x;
  const int b  = blockIdx.x / HO_;
  const int ho = blockIdx.x % HO_;
  for (int j = tid; j < CIN_ * WO_; j += 256) {
    int ci = j / WO_, wo = j - ci * WO_;
    xrow[j] = x[((b * CIN_ + ci) * H_ + 2 * ho) * W_ + 2 * wo];
  }
  for (int j = tid; j < 18 * CIN_; j += 256) owl[j] = ow[j];
  if (tid < 18) obl[tid] = ob[tid];
  __syncthreads();
  for (int i = tid; i < 18 * WO_; i += 256) {
    int o = i / WO_, wo = i - o * WO_;
    float acc = obl[o];
    const float* wr = &owl[o * CIN_];
    const float* xr = &xrow[wo];
#pragma unroll 4
    for (int ci = 0; ci < CIN_; ci++) acc += wr[ci] * xr[ci * WO_];
    off[((b * 18 + o) * HO_ + ho) * WO_ + wo] = acc;
  }
}

// ------------------------------------------------- KT: pack weights for MFMA
// K reordered as s' = kk*128 + ci. Apk[ks][m][quad][j] bf16, ks=0..35 (K/32),
// so a lane's A-frag (8 bf16) is one contiguous 16 B load; a wave's 16-row
// m-tile load is 1 KB fully coalesced.
__global__ __launch_bounds__(256) void k_pack(const float* __restrict__ dw,
                                              unsigned short* __restrict__ Apk) {
  int t = blockIdx.x * 256 + threadIdx.x;   // 0..294911
  int j  = t & 7;
  int qd = (t >> 3) & 3;
  int m  = (t >> 5) & 255;
  int ks = t >> 13;
  int k  = ks * 32 + qd * 8 + j;            // 0..1151 (reordered K)
  int kk = k >> 7, ci = k & 127;
  Apk[t] = f2bu(dw[m * SK_ + ci * KK_ + kk]);
}

// -------------------------------------------- K2: fused sampling + MFMA GEMM
// Block = (b, ho) row. 4 waves; wave w owns couts w*64..w*64+63, all 48 px
// (40 valid + 8 zero-padded). K-loop: 9 chunks (one kk each, 128 ci = 4
// MFMA k-steps of 32).
__global__ __launch_bounds__(256) void k_main(const float* __restrict__ x,
                                              const float* __restrict__ off,
                                              const unsigned short* __restrict__ Apk,
                                              const float* __restrict__ db,
                                              float* __restrict__ outp,
                                              float* __restrict__ accum) {
  __shared__ __align__(16) unsigned short smp[48 * 136];  // 13056 B [px][k-pad]
  __shared__ __align__(16) int   pidx[WO_ * KK_ * 4];     // 5760 B
  __shared__ __align__(16) float pw[WO_ * KK_ * 4];       // 5760 B

  const int tid = threadIdx.x;
  const int b  = blockIdx.x / HO_;
  const int ho = blockIdx.x % HO_;
  const int wv = tid >> 6;         // wave 0..3
  const int ln = tid & 63;
  const int lm = ln & 15;          // n / m row within tile
  const int qd = ln >> 4;          // quad 0..3
  const int wbase = wv * 64;       // cout base for this wave

  // zero the 8 padded px rows (never written again)
  for (int i = tid; i < 8 * 136; i += 256) smp[40 * 136 + i] = 0;

  // Precompute per-(px,kk): clipped corner indices + masked bilinear weights.
  for (int i = tid; i < WO_ * KK_; i += 256) {
    int px = i / KK_, kk = i - px * KK_;
    float dy = off[((b * 18 + 2 * kk) * HO_ + ho) * WO_ + px];
    float dx = off[((b * 18 + 2 * kk + 1) * HO_ + ho) * WO_ + px];
    float py  = (float)(2 * ho - 1 + (kk / 3)) + dy;
    float pxf = (float)(2 * px - 1 + (kk % 3)) + dx;
    float y0f = floorf(py), x0f = floorf(pxf);
    float wy1 = py - y0f, wx1 = pxf - x0f;
    float wy0 = 1.f - wy1, wx0 = 1.f - wx1;
    int y0 = (int)y0f, x0 = (int)x0f;
    int y1 = y0 + 1, x1 = x0 + 1;
    bool vy0 = (y0 >= 0) && (y0 < H_);
    bool vy1 = (y1 >= 0) && (y1 < H_);
    bool vx0 = (x0 >= 0) && (x0 < W_);
    bool vx1 = (x1 >= 0) && (x1 < W_);
    int y0c = min(max(y0, 0), H_ - 1), y1c = min(max(y1, 0), H_ - 1);
    int x0c = min(max(x0, 0), W_ - 1), x1c = min(max(x1, 0), W_ - 1);
    pidx[i * 4 + 0] = y0c * W_ + x0c;  pw[i * 4 + 0] = (vy0 && vx0) ? wy0 * wx0 : 0.f;
    pidx[i * 4 + 1] = y0c * W_ + x1c;  pw[i * 4 + 1] = (vy0 && vx1) ? wy0 * wx1 : 0.f;
    pidx[i * 4 + 2] = y1c * W_ + x0c;  pw[i * 4 + 2] = (vy1 && vx0) ? wy1 * wx0 : 0.f;
    pidx[i * 4 + 3] = y1c * W_ + x1c;  pw[i * 4 + 3] = (vy1 && vx1) ? wy1 * wx1 : 0.f;
  }

  floatx4 acc[4][3];
#pragma unroll
  for (int mt = 0; mt < 4; mt++)
#pragma unroll
    for (int nt = 0; nt < 3; nt++) acc[mt][nt] = (floatx4){0.f, 0.f, 0.f, 0.f};

  const float* xb = x + (size_t)b * CIN_ * H_ * W_;

  for (int kkc = 0; kkc < KK_; kkc++) {
    __syncthreads();   // smp safe to overwrite (covers precompute on kkc=0)
    // phase 1: sample 40 px x 128 ci for this kk into LDS (bf16)
#pragma unroll
    for (int it = 0; it < 20; it++) {
      int j = tid + it * 256;
      int ci = j / 40;
      int px = j - ci * 40;
      int4   I  = *(const int4*)&pidx[(px * KK_ + kkc) * 4];
      float4 Wv = *(const float4*)&pw[(px * KK_ + kkc) * 4];
      const float* xp = xb + ci * (H_ * W_);
      float s = Wv.x * xp[I.x] + Wv.y * xp[I.y] + Wv.z * xp[I.z] + Wv.w * xp[I.w];
      smp[px * 136 + ci] = f2bu(s);
    }
    __syncthreads();
    // phase 2: 4 MFMA k-steps over the 128 ci of this kk
#pragma unroll
    for (int q = 0; q < 4; q++) {
      const int ks = kkc * 4 + q;
      const unsigned short* ap = Apk + ks * 8192 + (wbase + lm) * 32 + qd * 8;
      short8 a0 = *(const short8*)(ap + 0 * 16 * 32);
      short8 a1 = *(const short8*)(ap + 1 * 16 * 32);
      short8 a2 = *(const short8*)(ap + 2 * 16 * 32);
      short8 a3 = *(const short8*)(ap + 3 * 16 * 32);
      const unsigned short* bp = smp + lm * 136 + q * 32 + qd * 8;
      short8 b0 = *(const short8*)(bp + 0 * 16 * 136);
      short8 b1 = *(const short8*)(bp + 1 * 16 * 136);
      short8 b2 = *(const short8*)(bp + 2 * 16 * 136);
      acc[0][0] = __builtin_amdgcn_mfma_f32_16x16x32_bf16(a0, b0, acc[0][0], 0, 0, 0);
      acc[0][1] = __builtin_amdgcn_mfma_f32_16x16x32_bf16(a0, b1, acc[0][1], 0, 0, 0);
      acc[0][2] = __builtin_amdgcn_mfma_f32_16x16x32_bf16(a0, b2, acc[0][2], 0, 0, 0);
      acc[1][0] = __builtin_amdgcn_mfma_f32_16x16x32_bf16(a1, b0, acc[1][0], 0, 0, 0);
      acc[1][1] = __builtin_amdgcn_mfma_f32_16x16x32_bf16(a1, b1, acc[1][1], 0, 0, 0);
      acc[1][2] = __builtin_amdgcn_mfma_f32_16x16x32_bf16(a1, b2, acc[1][2], 0, 0, 0);
      acc[2][0] = __builtin_amdgcn_mfma_f32_16x16x32_bf16(a2, b0, acc[2][0], 0, 0, 0);
      acc[2][1] = __builtin_amdgcn_mfma_f32_16x16x32_bf16(a2, b1, acc[2][1], 0, 0, 0);
      acc[2][2] = __builtin_amdgcn_mfma_f32_16x16x32_bf16(a2, b2, acc[2][2], 0, 0, 0);
      acc[3][0] = __builtin_amdgcn_mfma_f32_16x16x32_bf16(a3, b0, acc[3][0], 0, 0, 0);
      acc[3][1] = __builtin_amdgcn_mfma_f32_16x16x32_bf16(a3, b1, acc[3][1], 0, 0, 0);
      acc[3][2] = __builtin_amdgcn_mfma_f32_16x16x32_bf16(a3, b2, acc[3][2], 0, 0, 0);
    }
  }

  // Epilogue. C/D layout: col(lane&15)=px-within-ntile, row(qd*4+reg)=cout
  // within mtile. Wave owns disjoint couts -> no cross-wave reduction.
  float bias[16];
#pragma unroll
  for (int mt = 0; mt < 4; mt++)
#pragma unroll
    for (int r = 0; r < 4; r++) bias[mt * 4 + r] = db[wbase + mt * 16 + qd * 4 + r];

  float s1[16], s2[16];
#pragma unroll
  for (int i = 0; i < 16; i++) { s1[i] = 0.f; s2[i] = 0.f; }

#pragma unroll
  for (int mt = 0; mt < 4; mt++) {
#pragma unroll
    for (int nt = 0; nt < 3; nt++) {
      int px = nt * 16 + lm;
      bool valid = px < WO_;
#pragma unroll
      for (int r = 0; r < 4; r++) {
        int c = wbase + mt * 16 + qd * 4 + r;
        float v = acc[mt][nt][r] + bias[mt * 4 + r];
        if (valid) {
          outp[(((size_t)b * COUT_ + c) * HO_ + ho) * WO_ + px] = v;
          s1[mt * 4 + r] += v;
          s2[mt * 4 + r] += v * v;
        }
      }
    }
  }
  // reduce over the 16 lanes of each quad (xor bits 0..3)
#pragma unroll
  for (int d = 1; d < 16; d <<= 1) {
#pragma unroll
    for (int i = 0; i < 16; i++) {
      s1[i] += __shfl_xor(s1[i], d, 64);
      s2[i] += __shfl_xor(s2[i], d, 64);
    }
  }
  if (lm == 0) {
#pragma unroll
    for (int i = 0; i < 16; i++) {
      int c = wbase + (i >> 2) * 16 + qd * 4 + (i & 3);
      atomicAdd(&accum[c], s1[i]);
      atomicAdd(&accum[COUT_ + c], s2[i]);
    }
  }
}

// --------------------------------------------------- K3: BN + SiLU, in place
__global__ __launch_bounds__(256) void k_bn(float* __restrict__ io,
                                            const float* __restrict__ accum,
                                            const float* __restrict__ gamma,
                                            const float* __restrict__ beta) {
  const int t = blockIdx.x * 256 + threadIdx.x;
  const int i0 = t * 4;
  const int c = (i0 / (HO_ * WO_)) % COUT_;
  const float mean = accum[c] * (1.f / NPIX_);
  const float var  = accum[COUT_ + c] * (1.f / NPIX_) - mean * mean;
  const float inv  = rsqrtf(var + 1e-5f);
  const float g  = gamma[c] * inv;
  const float be = beta[c] - mean * g;
  float4 r = *(const float4*)(io + i0);
  float v[4] = {r.x, r.y, r.z, r.w};
#pragma unroll
  for (int q = 0; q < 4; q++) {
    float u = v[q] * g + be;
    v[q] = u / (1.f + expf(-u));
  }
  *(float4*)(io + i0) = make_float4(v[0], v[1], v[2], v[3]);
}

// ----------------------------------------------------------------- launcher
extern "C" void kernel_launch(void* const* d_in, const int* in_sizes, int n_in,
                              void* d_out, int out_size, void* d_ws, size_t ws_size,
                              hipStream_t stream) {
  const float* x     = (const float*)d_in[0];
  const float* ow    = (const float*)d_in[1];
  const float* ob    = (const float*)d_in[2];
  const float* dw    = (const float*)d_in[3];
  const float* db    = (const float*)d_in[4];
  const float* gamma = (const float*)d_in[5];
  const float* beta  = (const float*)d_in[6];
  float* out = (float*)d_out;

  float* off   = (float*)d_ws;                       // 460800 floats
  float* accum = off + B_ * 18 * HO_ * WO_;          // 512 floats
  unsigned short* Apk = (unsigned short*)(accum + 2 * COUT_);  // 294912 ushorts

  hipMemsetAsync(accum, 0, 2 * COUT_ * sizeof(float), stream);
  k_offsets<<<B_ * HO_, 256, 0, stream>>>(x, ow, ob, off);
  k_pack<<<SK_, 256, 0, stream>>>(dw, Apk);
  k_main<<<B_ * HO_, 256, 0, stream>>>(x, off, Apk, db, out, accum);
  k_bn<<<(NPIX_ * COUT_ / 4 + 255) / 256, 256, 0, stream>>>(
      out, accum, gamma, beta);
}

// Round 4
// 317.552 us; speedup vs baseline: 1.4704x; 1.4448x over previous
//
#include <hip/hip_runtime.h>
#include <hip/hip_bf16.h>

#define B_    16
#define CIN_  128
#define COUT_ 256
#define H_    80
#define W_    80
#define HO_   40
#define WO_   40
#define KK_   9
#define SK_   1152      // CIN_*KK_
#define NPIX_ 25600     // B_*HO_*WO_
#define NKS_  36        // K / 32

typedef __attribute__((ext_vector_type(8))) short short8;
typedef __attribute__((ext_vector_type(4))) float floatx4;

__device__ __forceinline__ unsigned short f2bu(float v) {
  __hip_bfloat16 h = __float2bfloat16(v);
  return *reinterpret_cast<unsigned short*>(&h);
}

// ---------------------------------------------------------------- K1: offsets
__global__ __launch_bounds__(256) void k_offsets(const float* __restrict__ x,
                                                 const float* __restrict__ ow,
                                                 const float* __restrict__ ob,
                                                 float* __restrict__ off) {
  __shared__ float xrow[CIN_ * WO_];
  __shared__ float owl[18 * CIN_];
  __shared__ float obl[18];
  const int tid = threadIdx.x;
  const int b  = blockIdx.x / HO_;
  const int ho = blockIdx.x % HO_;
  for (int j = tid; j < CIN_ * WO_; j += 256) {
    int ci = j / WO_, wo = j - ci * WO_;
    xrow[j] = x[((b * CIN_ + ci) * H_ + 2 * ho) * W_ + 2 * wo];
  }
  for (int j = tid; j < 18 * CIN_; j += 256) owl[j] = ow[j];
  if (tid < 18) obl[tid] = ob[tid];
  __syncthreads();
  for (int i = tid; i < 18 * WO_; i += 256) {
    int o = i / WO_, wo = i - o * WO_;
    float acc = obl[o];
    const float* wr = &owl[o * CIN_];
    const float* xr = &xrow[wo];
#pragma unroll 4
    for (int ci = 0; ci < CIN_; ci++) acc += wr[ci] * xr[ci * WO_];
    off[((b * 18 + o) * HO_ + ho) * WO_ + wo] = acc;
  }
}

// ------------------------------------------------- KT: pack weights for MFMA
// (verified round 3) K reordered as s' = kk*128 + ci. Apk[ks][m][quad][j] bf16.
__global__ __launch_bounds__(256) void k_pack(const float* __restrict__ dw,
                                              unsigned short* __restrict__ Apk) {
  int t = blockIdx.x * 256 + threadIdx.x;   // 0..294911
  int j  = t & 7;
  int qd = (t >> 3) & 3;
  int m  = (t >> 5) & 255;
  int ks = t >> 13;
  int k  = ks * 32 + qd * 8 + j;
  int kk = k >> 7, ci = k & 127;
  Apk[t] = f2bu(dw[m * SK_ + ci * KK_ + kk]);
}

// ------------------------------------------------------ K2a: deform sampling
// Block = (b, kk, ho-pair). Writes samples directly in MFMA B-fragment
// order: Spk[(pt*36+ks)*512 + (qd*16+lm)*8 + j] where p = pt*16+lm is the
// flat pixel, k = ks*32 + qd*8 + j. Each thread emits one 16B short8 store.
__global__ __launch_bounds__(256) void k_sample(const float* __restrict__ x,
                                                const float* __restrict__ off,
                                                unsigned short* __restrict__ Spk) {
  __shared__ __align__(16) int   pidx[80 * 4];
  __shared__ __align__(16) float pw[80 * 4];
  const int tid = threadIdx.x;
  const int bid = blockIdx.x;          // b*180 + kk*20 + g
  const int g  = bid % 20;
  const int kk = (bid / 20) % KK_;
  const int b  = bid / 180;
  const int ho0 = g * 2;

  if (tid < 80) {
    int hop = tid / 40, px = tid % 40;
    int ho = ho0 + hop;
    float dy = off[((b * 18 + 2 * kk) * HO_ + ho) * WO_ + px];
    float dx = off[((b * 18 + 2 * kk + 1) * HO_ + ho) * WO_ + px];
    float py  = (float)(2 * ho - 1 + (kk / 3)) + dy;
    float pxf = (float)(2 * px - 1 + (kk % 3)) + dx;
    float y0f = floorf(py), x0f = floorf(pxf);
    float wy1 = py - y0f, wx1 = pxf - x0f;
    float wy0 = 1.f - wy1, wx0 = 1.f - wx1;
    int y0 = (int)y0f, x0 = (int)x0f;
    int y1 = y0 + 1, x1 = x0 + 1;
    bool vy0 = (y0 >= 0) && (y0 < H_);
    bool vy1 = (y1 >= 0) && (y1 < H_);
    bool vx0 = (x0 >= 0) && (x0 < W_);
    bool vx1 = (x1 >= 0) && (x1 < W_);
    int y0c = min(max(y0, 0), H_ - 1), y1c = min(max(y1, 0), H_ - 1);
    int x0c = min(max(x0, 0), W_ - 1), x1c = min(max(x1, 0), W_ - 1);
    pidx[tid * 4 + 0] = y0c * W_ + x0c;  pw[tid * 4 + 0] = (vy0 && vx0) ? wy0 * wx0 : 0.f;
    pidx[tid * 4 + 1] = y0c * W_ + x1c;  pw[tid * 4 + 1] = (vy0 && vx1) ? wy0 * wx1 : 0.f;
    pidx[tid * 4 + 2] = y1c * W_ + x0c;  pw[tid * 4 + 2] = (vy1 && vx0) ? wy1 * wx0 : 0.f;
    pidx[tid * 4 + 3] = y1c * W_ + x1c;  pw[tid * 4 + 3] = (vy1 && vx1) ? wy1 * wx1 : 0.f;
  }
  __syncthreads();

  const float* xb = x + (size_t)b * CIN_ * H_ * W_;
#pragma unroll
  for (int it = 0; it < 5; it++) {
    int idx = it * 256 + tid;          // 0..1279: (oct, hop, px)
    int px  = idx % 40;
    int hop = (idx / 40) & 1;
    int oct = idx / 80;                // ci octet 0..15
    int4   I  = *(const int4*)&pidx[(hop * 40 + px) * 4];
    float4 Wv = *(const float4*)&pw[(hop * 40 + px) * 4];
    int p  = b * 1600 + (ho0 + hop) * 40 + px;
    int pt = p >> 4, lm = p & 15;
    int ks = kk * 4 + (oct >> 2);
    int qd = oct & 3;
    const float* xp = xb + (oct * 8) * (H_ * W_);
    short8 r;
#pragma unroll
    for (int i2 = 0; i2 < 8; i2++) {
      const float* q = xp + i2 * (H_ * W_);
      float s = Wv.x * q[I.x] + Wv.y * q[I.y] + Wv.z * q[I.z] + Wv.w * q[I.w];
      r[i2] = (short)f2bu(s);
    }
    *(short8*)&Spk[(((size_t)pt * NKS_ + ks) * 64 + qd * 16 + lm) * 8] = r;
  }
}

// ---------------------------------------------------- K2b: MFMA GEMM (no LDS)
// Block = 128 threads (2 waves). blockIdx: (px-group of 64) x (cout half).
// Wave: 64 couts x 64 px = 4x4 tiles of 16x16x32 MFMA, K = 36 steps.
__global__ __launch_bounds__(128) void k_gemm(const unsigned short* __restrict__ Apk,
                                              const unsigned short* __restrict__ Spk,
                                              const float* __restrict__ db,
                                              float* __restrict__ outp,
                                              float* __restrict__ accum) {
  const int tid = threadIdx.x;
  const int wv = tid >> 6;
  const int ln = tid & 63;
  const int lm = ln & 15;
  const int qd = ln >> 4;
  const int gblk = blockIdx.x >> 1;        // 0..399  (64-px group)
  const int chlf = blockIdx.x & 1;         // cout half
  const int pt0  = gblk * 4;
  const int cbase = chlf * 128 + wv * 64;

  floatx4 acc[4][4];
#pragma unroll
  for (int mt = 0; mt < 4; mt++)
#pragma unroll
    for (int nt = 0; nt < 4; nt++) acc[mt][nt] = (floatx4){0.f, 0.f, 0.f, 0.f};

  const unsigned short* ap0 = Apk + (cbase + lm) * 32 + qd * 8;      // +ks*8192 +mt*512
  const unsigned short* bp0 = Spk + (size_t)pt0 * NKS_ * 512 + ln * 8; // +ks*512 +nt*36*512

  short8 A[2][4], Bv[2][4];
#pragma unroll
  for (int mt = 0; mt < 4; mt++) A[0][mt] = *(const short8*)(ap0 + mt * 512);
#pragma unroll
  for (int nt = 0; nt < 4; nt++) Bv[0][nt] = *(const short8*)(bp0 + (size_t)nt * NKS_ * 512);

  for (int ks = 0; ks < NKS_; ks++) {
    const int cur = ks & 1, nxt = cur ^ 1;
    if (ks < NKS_ - 1) {
      const unsigned short* apn = ap0 + (ks + 1) * 8192;
      const unsigned short* bpn = bp0 + (ks + 1) * 512;
#pragma unroll
      for (int mt = 0; mt < 4; mt++) A[nxt][mt] = *(const short8*)(apn + mt * 512);
#pragma unroll
      for (int nt = 0; nt < 4; nt++) Bv[nxt][nt] = *(const short8*)(bpn + (size_t)nt * NKS_ * 512);
    }
#pragma unroll
    for (int mt = 0; mt < 4; mt++)
#pragma unroll
      for (int nt = 0; nt < 4; nt++)
        acc[mt][nt] = __builtin_amdgcn_mfma_f32_16x16x32_bf16(A[cur][mt], Bv[cur][nt],
                                                              acc[mt][nt], 0, 0, 0);
  }

  // Epilogue: bias, store pre-BN fp32, per-cout stats (verified round 3).
  float bias[16];
#pragma unroll
  for (int mt = 0; mt < 4; mt++)
#pragma unroll
    for (int r = 0; r < 4; r++) bias[mt * 4 + r] = db[cbase + mt * 16 + qd * 4 + r];

  float s1[16], s2[16];
#pragma unroll
  for (int i = 0; i < 16; i++) { s1[i] = 0.f; s2[i] = 0.f; }

#pragma unroll
  for (int nt = 0; nt < 4; nt++) {
    int p = (pt0 + nt) * 16 + lm;
    int bb = p / 1600, rem = p % 1600;
    float* ob = outp + (size_t)bb * COUT_ * 1600 + rem;
#pragma unroll
    for (int mt = 0; mt < 4; mt++) {
#pragma unroll
      for (int r = 0; r < 4; r++) {
        int c = cbase + mt * 16 + qd * 4 + r;
        float v = acc[mt][nt][r] + bias[mt * 4 + r];
        ob[(size_t)c * 1600] = v;
        s1[mt * 4 + r] += v;
        s2[mt * 4 + r] += v * v;
      }
    }
  }
#pragma unroll
  for (int d = 1; d < 16; d <<= 1) {
#pragma unroll
    for (int i = 0; i < 16; i++) {
      s1[i] += __shfl_xor(s1[i], d, 64);
      s2[i] += __shfl_xor(s2[i], d, 64);
    }
  }
  if (lm == 0) {
#pragma unroll
    for (int i = 0; i < 16; i++) {
      int c = cbase + (i >> 2) * 16 + qd * 4 + (i & 3);
      atomicAdd(&accum[c], s1[i]);
      atomicAdd(&accum[COUT_ + c], s2[i]);
    }
  }
}

// --------------------------------------------------- K3: BN + SiLU, in place
__global__ __launch_bounds__(256) void k_bn(float* __restrict__ io,
                                            const float* __restrict__ accum,
                                            const float* __restrict__ gamma,
                                            const float* __restrict__ beta) {
  const int t = blockIdx.x * 256 + threadIdx.x;
  const int i0 = t * 4;
  const int c = (i0 / (HO_ * WO_)) % COUT_;
  const float mean = accum[c] * (1.f / NPIX_);
  const float var  = accum[COUT_ + c] * (1.f / NPIX_) - mean * mean;
  const float inv  = rsqrtf(var + 1e-5f);
  const float g  = gamma[c] * inv;
  const float be = beta[c] - mean * g;
  float4 r = *(const float4*)(io + i0);
  float v[4] = {r.x, r.y, r.z, r.w};
#pragma unroll
  for (int q = 0; q < 4; q++) {
    float u = v[q] * g + be;
    v[q] = u / (1.f + expf(-u));
  }
  *(float4*)(io + i0) = make_float4(v[0], v[1], v[2], v[3]);
}

// ----------------------------------------------------------------- launcher
extern "C" void kernel_launch(void* const* d_in, const int* in_sizes, int n_in,
                              void* d_out, int out_size, void* d_ws, size_t ws_size,
                              hipStream_t stream) {
  const float* x     = (const float*)d_in[0];
  const float* ow    = (const float*)d_in[1];
  const float* ob    = (const float*)d_in[2];
  const float* dw    = (const float*)d_in[3];
  const float* db    = (const float*)d_in[4];
  const float* gamma = (const float*)d_in[5];
  const float* beta  = (const float*)d_in[6];
  float* out = (float*)d_out;

  float* off   = (float*)d_ws;                                 // 460800 floats
  float* accum = off + B_ * 18 * HO_ * WO_;                    // 512 floats
  unsigned short* Apk = (unsigned short*)(accum + 2 * COUT_);  // 294912 ushorts
  unsigned short* Spk = Apk + (size_t)SK_ * COUT_;             // 29491200 ushorts (59 MB)

  hipMemsetAsync(accum, 0, 2 * COUT_ * sizeof(float), stream);
  k_offsets<<<B_ * HO_, 256, 0, stream>>>(x, ow, ob, off);
  k_pack<<<SK_, 256, 0, stream>>>(dw, Apk);
  k_sample<<<B_ * KK_ * 20, 256, 0, stream>>>(x, off, Spk);
  k_gemm<<<800, 128, 0, stream>>>(Apk, Spk, db, out, accum);
  k_bn<<<(NPIX_ * COUT_ / 4 + 255) / 256, 256, 0, stream>>>(
      out, accum, gamma, beta);
}

// Round 5
// 305.395 us; speedup vs baseline: 1.5289x; 1.0398x over previous
//
#include <hip/hip_runtime.h>
#include <hip/hip_bf16.h>

#define B_    16
#define CIN_  128
#define COUT_ 256
#define H_    80
#define W_    80
#define HO_   40
#define WO_   40
#define KK_   9
#define SK_   1152      // CIN_*KK_
#define NPIX_ 25600     // B_*HO_*WO_
#define NKS_  36        // K / 32

typedef __attribute__((ext_vector_type(8))) short short8;
typedef __attribute__((ext_vector_type(4))) float floatx4;

__device__ __forceinline__ unsigned short f2bu(float v) {
  __hip_bfloat16 h = __float2bfloat16(v);
  return *reinterpret_cast<unsigned short*>(&h);
}

// ---------------------------------------------------------------- K1: offsets
__global__ __launch_bounds__(256) void k_offsets(const float* __restrict__ x,
                                                 const float* __restrict__ ow,
                                                 const float* __restrict__ ob,
                                                 float* __restrict__ off) {
  __shared__ float xrow[CIN_ * WO_];
  __shared__ float owl[18 * CIN_];
  __shared__ float obl[18];
  const int tid = threadIdx.x;
  const int b  = blockIdx.x / HO_;
  const int ho = blockIdx.x % HO_;
  for (int j = tid; j < CIN_ * WO_; j += 256) {
    int ci = j / WO_, wo = j - ci * WO_;
    xrow[j] = x[((b * CIN_ + ci) * H_ + 2 * ho) * W_ + 2 * wo];
  }
  for (int j = tid; j < 18 * CIN_; j += 256) owl[j] = ow[j];
  if (tid < 18) obl[tid] = ob[tid];
  __syncthreads();
  for (int i = tid; i < 18 * WO_; i += 256) {
    int o = i / WO_, wo = i - o * WO_;
    float acc = obl[o];
    const float* wr = &owl[o * CIN_];
    const float* xr = &xrow[wo];
#pragma unroll 4
    for (int ci = 0; ci < CIN_; ci++) acc += wr[ci] * xr[ci * WO_];
    off[((b * 18 + o) * HO_ + ho) * WO_ + wo] = acc;
  }
}

// ------------------------------------------------- KT: pack weights for MFMA
// (verified round 3) K reordered as s' = kk*128 + ci. Apk[ks][m][quad][j] bf16.
__global__ __launch_bounds__(256) void k_pack(const float* __restrict__ dw,
                                              unsigned short* __restrict__ Apk) {
  int t = blockIdx.x * 256 + threadIdx.x;   // 0..294911
  int j  = t & 7;
  int qd = (t >> 3) & 3;
  int m  = (t >> 5) & 255;
  int ks = t >> 13;
  int k  = ks * 32 + qd * 8 + j;
  int kk = k >> 7, ci = k & 127;
  Apk[t] = f2bu(dw[m * SK_ + ci * KK_ + kk]);
}

// ------------------------------------------------------ K2a: deform sampling
// Logical block = (b, g=ho-pair, kk). blockIdx remapped so all blocks of one
// batch image b land on ONE XCD (x per image = 3.3 MB < 4 MB L2), with kk
// innermost so consecutive blocks on an XCD reuse the same x rows.
// Writes samples directly in MFMA B-fragment order (verified round 4).
__global__ __launch_bounds__(256) void k_sample(const float* __restrict__ x,
                                                const float* __restrict__ off,
                                                unsigned short* __restrict__ Spk) {
  __shared__ __align__(16) int   pidx[80 * 4];
  __shared__ __align__(16) float pw[80 * 4];
  const int tid = threadIdx.x;
  const int j0   = blockIdx.x;         // 0..2879
  const int xcd  = j0 & 7;
  const int s    = j0 >> 3;            // 0..359
  const int b_hi = s / 180;
  const int t0   = s % 180;
  const int g    = t0 / 9;
  const int kk   = t0 % 9;
  const int b    = b_hi * 8 + xcd;
  const int ho0 = g * 2;

  if (tid < 80) {
    int hop = tid / 40, px = tid % 40;
    int ho = ho0 + hop;
    float dy = off[((b * 18 + 2 * kk) * HO_ + ho) * WO_ + px];
    float dx = off[((b * 18 + 2 * kk + 1) * HO_ + ho) * WO_ + px];
    float py  = (float)(2 * ho - 1 + (kk / 3)) + dy;
    float pxf = (float)(2 * px - 1 + (kk % 3)) + dx;
    float y0f = floorf(py), x0f = floorf(pxf);
    float wy1 = py - y0f, wx1 = pxf - x0f;
    float wy0 = 1.f - wy1, wx0 = 1.f - wx1;
    int y0 = (int)y0f, x0 = (int)x0f;
    int y1 = y0 + 1, x1 = x0 + 1;
    bool vy0 = (y0 >= 0) && (y0 < H_);
    bool vy1 = (y1 >= 0) && (y1 < H_);
    bool vx0 = (x0 >= 0) && (x0 < W_);
    bool vx1 = (x1 >= 0) && (x1 < W_);
    int y0c = min(max(y0, 0), H_ - 1), y1c = min(max(y1, 0), H_ - 1);
    int x0c = min(max(x0, 0), W_ - 1), x1c = min(max(x1, 0), W_ - 1);
    pidx[tid * 4 + 0] = y0c * W_ + x0c;  pw[tid * 4 + 0] = (vy0 && vx0) ? wy0 * wx0 : 0.f;
    pidx[tid * 4 + 1] = y0c * W_ + x1c;  pw[tid * 4 + 1] = (vy0 && vx1) ? wy0 * wx1 : 0.f;
    pidx[tid * 4 + 2] = y1c * W_ + x0c;  pw[tid * 4 + 2] = (vy1 && vx0) ? wy1 * wx0 : 0.f;
    pidx[tid * 4 + 3] = y1c * W_ + x1c;  pw[tid * 4 + 3] = (vy1 && vx1) ? wy1 * wx1 : 0.f;
  }
  __syncthreads();

  const float* xb = x + (size_t)b * CIN_ * H_ * W_;
#pragma unroll
  for (int it = 0; it < 5; it++) {
    int idx = it * 256 + tid;          // 0..1279: (oct, hop, px)
    int px  = idx % 40;
    int hop = (idx / 40) & 1;
    int oct = idx / 80;                // ci octet 0..15
    int4   I  = *(const int4*)&pidx[(hop * 40 + px) * 4];
    float4 Wv = *(const float4*)&pw[(hop * 40 + px) * 4];
    int p  = b * 1600 + (ho0 + hop) * 40 + px;
    int pt = p >> 4, lm = p & 15;
    int ks = kk * 4 + (oct >> 2);
    int qd = oct & 3;
    const float* xp = xb + (oct * 8) * (H_ * W_);
    short8 r;
#pragma unroll
    for (int i2 = 0; i2 < 8; i2++) {
      const float* q = xp + i2 * (H_ * W_);
      float s2 = Wv.x * q[I.x] + Wv.y * q[I.y] + Wv.z * q[I.z] + Wv.w * q[I.w];
      r[i2] = (short)f2bu(s2);
    }
    *(short8*)&Spk[(((size_t)pt * NKS_ + ks) * 64 + qd * 16 + lm) * 8] = r;
  }
}

// ---------------------------------------------------- K2b: MFMA GEMM (no LDS)
// Block = 256 threads (4 waves) = one 16-px tile x all 256 couts. Wave wv
// owns couts wv*64..+63 (4 m-tiles). All waves share the B-frag (L1-hot).
// 4-deep register prefetch ring hides ~500cyc L2/L3 load latency.
__global__ __launch_bounds__(256) void k_gemm(const unsigned short* __restrict__ Apk,
                                              const unsigned short* __restrict__ Spk,
                                              const float* __restrict__ db,
                                              float* __restrict__ outp) {
  const int tid = threadIdx.x;
  const int wv = tid >> 6;
  const int ln = tid & 63;
  const int lm = ln & 15;
  const int qd = ln >> 4;
  const int pt = blockIdx.x;               // 0..1599 (16-px tile)
  const int cbase = wv * 64;

  floatx4 acc[4];
#pragma unroll
  for (int mt = 0; mt < 4; mt++) acc[mt] = (floatx4){0.f, 0.f, 0.f, 0.f};

  const unsigned short* ap0 = Apk + (cbase + lm) * 32 + qd * 8;   // +ks*8192 +mt*512
  const unsigned short* bp0 = Spk + (size_t)pt * NKS_ * 512 + ln * 8;  // +ks*512

  short8 A[4][4];
  short8 Bv[4];
#pragma unroll
  for (int st = 0; st < 3; st++) {
    const unsigned short* ap = ap0 + st * 8192;
#pragma unroll
    for (int mt = 0; mt < 4; mt++) A[st][mt] = *(const short8*)(ap + mt * 512);
    Bv[st] = *(const short8*)(bp0 + st * 512);
  }

#pragma unroll 4
  for (int ks = 0; ks < NKS_; ks++) {
    const int st = ks & 3;
    if (ks + 3 < NKS_) {
      const int sn = (ks + 3) & 3;
      const unsigned short* ap = ap0 + (ks + 3) * 8192;
#pragma unroll
      for (int mt = 0; mt < 4; mt++) A[sn][mt] = *(const short8*)(ap + mt * 512);
      Bv[sn] = *(const short8*)(bp0 + (ks + 3) * 512);
    }
#pragma unroll
    for (int mt = 0; mt < 4; mt++)
      acc[mt] = __builtin_amdgcn_mfma_f32_16x16x32_bf16(A[st][mt], Bv[st], acc[mt], 0, 0, 0);
  }

  // Epilogue: bias + pre-BN fp32 store. C/D layout: col=lane&15 -> px,
  // row=qd*4+reg -> cout (verified rounds 3-4).
  const int p = pt * 16 + lm;
  const int bb = p / 1600, rem = p % 1600;
  float* ob = outp + (size_t)bb * COUT_ * 1600 + rem;
#pragma unroll
  for (int mt = 0; mt < 4; mt++) {
#pragma unroll
    for (int r = 0; r < 4; r++) {
      const int c = cbase + mt * 16 + qd * 4 + r;
      ob[(size_t)c * 1600] = acc[mt][r] + db[c];
    }
  }
}

// ----------------------------------------------- K2c: per-channel sum/sq-sum
// One block per cout channel; coalesced grid-stride read, no atomics.
__global__ __launch_bounds__(256) void k_stats(const float* __restrict__ io,
                                               float* __restrict__ accum) {
  const int c = blockIdx.x;
  const int tid = threadIdx.x;
  float s1 = 0.f, s2 = 0.f;
  for (int i = tid; i < NPIX_; i += 256) {
    int b = i / 1600, r = i - b * 1600;
    float v = io[((size_t)b * COUT_ + c) * 1600 + r];
    s1 += v;
    s2 += v * v;
  }
#pragma unroll
  for (int d = 1; d < 64; d <<= 1) {
    s1 += __shfl_xor(s1, d, 64);
    s2 += __shfl_xor(s2, d, 64);
  }
  __shared__ float rs[4], rq[4];
  if ((tid & 63) == 0) { rs[tid >> 6] = s1; rq[tid >> 6] = s2; }
  __syncthreads();
  if (tid == 0) {
    accum[c]         = rs[0] + rs[1] + rs[2] + rs[3];
    accum[COUT_ + c] = rq[0] + rq[1] + rq[2] + rq[3];
  }
}

// --------------------------------------------------- K3: BN + SiLU, in place
__global__ __launch_bounds__(256) void k_bn(float* __restrict__ io,
                                            const float* __restrict__ accum,
                                            const float* __restrict__ gamma,
                                            const float* __restrict__ beta) {
  const int t = blockIdx.x * 256 + threadIdx.x;
  const int i0 = t * 4;
  const int c = (i0 / (HO_ * WO_)) % COUT_;
  const float mean = accum[c] * (1.f / NPIX_);
  const float var  = accum[COUT_ + c] * (1.f / NPIX_) - mean * mean;
  const float inv  = rsqrtf(var + 1e-5f);
  const float g  = gamma[c] * inv;
  const float be = beta[c] - mean * g;
  float4 r = *(const float4*)(io + i0);
  float v[4] = {r.x, r.y, r.z, r.w};
#pragma unroll
  for (int q = 0; q < 4; q++) {
    float u = v[q] * g + be;
    v[q] = u / (1.f + expf(-u));
  }
  *(float4*)(io + i0) = make_float4(v[0], v[1], v[2], v[3]);
}

// ----------------------------------------------------------------- launcher
extern "C" void kernel_launch(void* const* d_in, const int* in_sizes, int n_in,
                              void* d_out, int out_size, void* d_ws, size_t ws_size,
                              hipStream_t stream) {
  const float* x     = (const float*)d_in[0];
  const float* ow    = (const float*)d_in[1];
  const float* ob    = (const float*)d_in[2];
  const float* dw    = (const float*)d_in[3];
  const float* db    = (const float*)d_in[4];
  const float* gamma = (const float*)d_in[5];
  const float* beta  = (const float*)d_in[6];
  float* out = (float*)d_out;

  float* off   = (float*)d_ws;                                 // 460800 floats
  float* accum = off + B_ * 18 * HO_ * WO_;                    // 512 floats
  unsigned short* Apk = (unsigned short*)(accum + 2 * COUT_);  // 294912 ushorts
  unsigned short* Spk = Apk + (size_t)SK_ * COUT_;             // 29491200 ushorts (59 MB)

  k_offsets<<<B_ * HO_, 256, 0, stream>>>(x, ow, ob, off);
  k_pack<<<SK_, 256, 0, stream>>>(dw, Apk);
  k_sample<<<B_ * KK_ * 20, 256, 0, stream>>>(x, off, Spk);
  k_gemm<<<NPIX_ / 16, 256, 0, stream>>>(Apk, Spk, db, out);
  k_stats<<<COUT_, 256, 0, stream>>>(out, accum);
  k_bn<<<(NPIX_ * COUT_ / 4 + 255) / 256, 256, 0, stream>>>(
      out, accum, gamma, beta);
}

// Round 6
// 269.869 us; speedup vs baseline: 1.7302x; 1.1316x over previous
//
#include <hip/hip_runtime.h>
#include <hip/hip_bf16.h>

#define B_    16
#define CIN_  128
#define COUT_ 256
#define H_    80
#define W_    80
#define HO_   40
#define WO_   40
#define KK_   9
#define SK_   1152      // CIN_*KK_
#define NPIX_ 25600     // B_*HO_*WO_
#define NKS_  36        // K / 32

typedef __attribute__((ext_vector_type(8))) short short8;
typedef __attribute__((ext_vector_type(4))) float floatx4;

__device__ __forceinline__ unsigned short f2bu(float v) {
  __hip_bfloat16 h = __float2bfloat16(v);
  return *reinterpret_cast<unsigned short*>(&h);
}
__device__ __forceinline__ float bu2f(unsigned short u) {
  return __uint_as_float(((unsigned)u) << 16);
}

// ---------------------------------------------------------------- K1: offsets
__global__ __launch_bounds__(256) void k_offsets(const float* __restrict__ x,
                                                 const float* __restrict__ ow,
                                                 const float* __restrict__ ob,
                                                 float* __restrict__ off) {
  __shared__ float xrow[CIN_ * WO_];
  __shared__ float owl[18 * CIN_];
  __shared__ float obl[18];
  const int tid = threadIdx.x;
  const int b  = blockIdx.x / HO_;
  const int ho = blockIdx.x % HO_;
  for (int j = tid; j < CIN_ * WO_; j += 256) {
    int ci = j / WO_, wo = j - ci * WO_;
    xrow[j] = x[((b * CIN_ + ci) * H_ + 2 * ho) * W_ + 2 * wo];
  }
  for (int j = tid; j < 18 * CIN_; j += 256) owl[j] = ow[j];
  if (tid < 18) obl[tid] = ob[tid];
  __syncthreads();
  for (int i = tid; i < 18 * WO_; i += 256) {
    int o = i / WO_, wo = i - o * WO_;
    float acc = obl[o];
    const float* wr = &owl[o * CIN_];
    const float* xr = &xrow[wo];
#pragma unroll 4
    for (int ci = 0; ci < CIN_; ci++) acc += wr[ci] * xr[ci * WO_];
    off[((b * 18 + o) * HO_ + ho) * WO_ + wo] = acc;
  }
}

// ------------------------------------------------- KT: pack weights for MFMA
// (verified round 3) K reordered as s' = kk*128 + ci. Apk[ks][m][quad][j] bf16.
__global__ __launch_bounds__(256) void k_pack(const float* __restrict__ dw,
                                              unsigned short* __restrict__ Apk) {
  int t = blockIdx.x * 256 + threadIdx.x;   // 0..294911
  int j  = t & 7;
  int qd = (t >> 3) & 3;
  int m  = (t >> 5) & 255;
  int ks = t >> 13;
  int k  = ks * 32 + qd * 8 + j;
  int kk = k >> 7, ci = k & 127;
  Apk[t] = f2bu(dw[m * SK_ + ci * KK_ + kk]);
}

// ---------------------------------------- KC: x -> channels-last bf16 (xcl)
// xcl[b][y][x][ci]. Block = (b, y): stage the 128ci x 80x row slab in LDS,
// write transposed so stores are contiguous 256B runs per x position.
__global__ __launch_bounds__(256) void k_cl(const float* __restrict__ x,
                                            unsigned short* __restrict__ xcl) {
  __shared__ float ts[CIN_][W_ + 1];
  const int tid = threadIdx.x;
  const int b = blockIdx.x / H_;
  const int y = blockIdx.x % H_;
  for (int j = tid; j < CIN_ * 20; j += 256) {
    int ci = j / 20, xq = j % 20;
    float4 v = *(const float4*)&x[(((size_t)b * CIN_ + ci) * H_ + y) * W_ + xq * 4];
    ts[ci][xq * 4 + 0] = v.x;
    ts[ci][xq * 4 + 1] = v.y;
    ts[ci][xq * 4 + 2] = v.z;
    ts[ci][xq * 4 + 3] = v.w;
  }
  __syncthreads();
  unsigned short* op = xcl + ((size_t)b * H_ * W_ + (size_t)y * W_) * CIN_;
  for (int j = tid; j < W_ * 32; j += 256) {
    int xx = j >> 5, cg = j & 31;
    unsigned short b0 = f2bu(ts[cg * 4 + 0][xx]);
    unsigned short b1 = f2bu(ts[cg * 4 + 1][xx]);
    unsigned short b2 = f2bu(ts[cg * 4 + 2][xx]);
    unsigned short b3 = f2bu(ts[cg * 4 + 3][xx]);
    uint2 pk = make_uint2((unsigned)b0 | ((unsigned)b1 << 16),
                          (unsigned)b2 | ((unsigned)b3 << 16));
    *(uint2*)(op + (size_t)xx * CIN_ + cg * 4) = pk;
  }
}

// ------------------------------------------ K2a: sampling from channels-last
// Block = (b, kk, ho-pair), XCD-swizzled by b. Unit = (pxh, oct): lanes
// consecutive in oct -> each corner load is 16 contiguous 16B loads (256B
// run), zero address divergence. Output in MFMA B-frag order (verified r4).
__global__ __launch_bounds__(256) void k_sample_cl(const unsigned short* __restrict__ xcl,
                                                   const float* __restrict__ off,
                                                   unsigned short* __restrict__ Spk) {
  __shared__ __align__(16) int   pidx[80 * 4];
  __shared__ __align__(16) float pw[80 * 4];
  const int tid = threadIdx.x;
  const int j0   = blockIdx.x;         // 0..2879
  const int xcd  = j0 & 7;
  const int s    = j0 >> 3;
  const int b_hi = s / 180;
  const int t0   = s % 180;
  const int g    = t0 / 9;
  const int kk   = t0 % 9;
  const int b    = b_hi * 8 + xcd;
  const int ho0  = g * 2;

  if (tid < 80) {
    int hop = tid / 40, px = tid % 40;
    int ho = ho0 + hop;
    float dy = off[((b * 18 + 2 * kk) * HO_ + ho) * WO_ + px];
    float dx = off[((b * 18 + 2 * kk + 1) * HO_ + ho) * WO_ + px];
    float py  = (float)(2 * ho - 1 + (kk / 3)) + dy;
    float pxf = (float)(2 * px - 1 + (kk % 3)) + dx;
    float y0f = floorf(py), x0f = floorf(pxf);
    float wy1 = py - y0f, wx1 = pxf - x0f;
    float wy0 = 1.f - wy1, wx0 = 1.f - wx1;
    int y0 = (int)y0f, x0 = (int)x0f;
    int y1 = y0 + 1, x1 = x0 + 1;
    bool vy0 = (y0 >= 0) && (y0 < H_);
    bool vy1 = (y1 >= 0) && (y1 < H_);
    bool vx0 = (x0 >= 0) && (x0 < W_);
    bool vx1 = (x1 >= 0) && (x1 < W_);
    int y0c = min(max(y0, 0), H_ - 1), y1c = min(max(y1, 0), H_ - 1);
    int x0c = min(max(x0, 0), W_ - 1), x1c = min(max(x1, 0), W_ - 1);
    pidx[tid * 4 + 0] = (y0c * W_ + x0c) << 7;  pw[tid * 4 + 0] = (vy0 && vx0) ? wy0 * wx0 : 0.f;
    pidx[tid * 4 + 1] = (y0c * W_ + x1c) << 7;  pw[tid * 4 + 1] = (vy0 && vx1) ? wy0 * wx1 : 0.f;
    pidx[tid * 4 + 2] = (y1c * W_ + x0c) << 7;  pw[tid * 4 + 2] = (vy1 && vx0) ? wy1 * wx0 : 0.f;
    pidx[tid * 4 + 3] = (y1c * W_ + x1c) << 7;  pw[tid * 4 + 3] = (vy1 && vx1) ? wy1 * wx1 : 0.f;
  }
  __syncthreads();

  const unsigned short* xb = xcl + (size_t)b * (H_ * W_ * CIN_);
#pragma unroll
  for (int it = 0; it < 5; it++) {
    int i = it * 256 + tid;            // (pxh, oct), oct fastest
    int oct = i & 15;
    int pxh = i >> 4;                  // 0..79
    int4   I  = *(const int4*)&pidx[pxh * 4];
    float4 Wv = *(const float4*)&pw[pxh * 4];
    short8 c00 = *(const short8*)(xb + I.x + oct * 8);
    short8 c01 = *(const short8*)(xb + I.y + oct * 8);
    short8 c10 = *(const short8*)(xb + I.z + oct * 8);
    short8 c11 = *(const short8*)(xb + I.w + oct * 8);
    short8 r;
#pragma unroll
    for (int i2 = 0; i2 < 8; i2++) {
      float v = Wv.x * bu2f((unsigned short)c00[i2]) +
                Wv.y * bu2f((unsigned short)c01[i2]) +
                Wv.z * bu2f((unsigned short)c10[i2]) +
                Wv.w * bu2f((unsigned short)c11[i2]);
      r[i2] = (short)f2bu(v);
    }
    int p  = b * 1600 + (ho0 + (pxh / 40)) * 40 + (pxh % 40);
    int pt = p >> 4, lm = p & 15;
    int ks = kk * 4 + (oct >> 2);
    int qd = oct & 3;
    *(short8*)&Spk[(((size_t)pt * NKS_ + ks) * 64 + qd * 16 + lm) * 8] = r;
  }
}

// ----------------------------------- K2a-fallback: fp32 gather (round 5 path)
__global__ __launch_bounds__(256) void k_sample(const float* __restrict__ x,
                                                const float* __restrict__ off,
                                                unsigned short* __restrict__ Spk) {
  __shared__ __align__(16) int   pidx[80 * 4];
  __shared__ __align__(16) float pw[80 * 4];
  const int tid = threadIdx.x;
  const int j0   = blockIdx.x;
  const int xcd  = j0 & 7;
  const int s    = j0 >> 3;
  const int b_hi = s / 180;
  const int t0   = s % 180;
  const int g    = t0 / 9;
  const int kk   = t0 % 9;
  const int b    = b_hi * 8 + xcd;
  const int ho0 = g * 2;

  if (tid < 80) {
    int hop = tid / 40, px = tid % 40;
    int ho = ho0 + hop;
    float dy = off[((b * 18 + 2 * kk) * HO_ + ho) * WO_ + px];
    float dx = off[((b * 18 + 2 * kk + 1) * HO_ + ho) * WO_ + px];
    float py  = (float)(2 * ho - 1 + (kk / 3)) + dy;
    float pxf = (float)(2 * px - 1 + (kk % 3)) + dx;
    float y0f = floorf(py), x0f = floorf(pxf);
    float wy1 = py - y0f, wx1 = pxf - x0f;
    float wy0 = 1.f - wy1, wx0 = 1.f - wx1;
    int y0 = (int)y0f, x0 = (int)x0f;
    int y1 = y0 + 1, x1 = x0 + 1;
    bool vy0 = (y0 >= 0) && (y0 < H_);
    bool vy1 = (y1 >= 0) && (y1 < H_);
    bool vx0 = (x0 >= 0) && (x0 < W_);
    bool vx1 = (x1 >= 0) && (x1 < W_);
    int y0c = min(max(y0, 0), H_ - 1), y1c = min(max(y1, 0), H_ - 1);
    int x0c = min(max(x0, 0), W_ - 1), x1c = min(max(x1, 0), W_ - 1);
    pidx[tid * 4 + 0] = y0c * W_ + x0c;  pw[tid * 4 + 0] = (vy0 && vx0) ? wy0 * wx0 : 0.f;
    pidx[tid * 4 + 1] = y0c * W_ + x1c;  pw[tid * 4 + 1] = (vy0 && vx1) ? wy0 * wx1 : 0.f;
    pidx[tid * 4 + 2] = y1c * W_ + x0c;  pw[tid * 4 + 2] = (vy1 && vx0) ? wy1 * wx0 : 0.f;
    pidx[tid * 4 + 3] = y1c * W_ + x1c;  pw[tid * 4 + 3] = (vy1 && vx1) ? wy1 * wx1 : 0.f;
  }
  __syncthreads();

  const float* xb = x + (size_t)b * CIN_ * H_ * W_;
#pragma unroll
  for (int it = 0; it < 5; it++) {
    int idx = it * 256 + tid;
    int px  = idx % 40;
    int hop = (idx / 40) & 1;
    int oct = idx / 80;
    int4   I  = *(const int4*)&pidx[(hop * 40 + px) * 4];
    float4 Wv = *(const float4*)&pw[(hop * 40 + px) * 4];
    int p  = b * 1600 + (ho0 + hop) * 40 + px;
    int pt = p >> 4, lm = p & 15;
    int ks = kk * 4 + (oct >> 2);
    int qd = oct & 3;
    const float* xp = xb + (oct * 8) * (H_ * W_);
    short8 r;
#pragma unroll
    for (int i2 = 0; i2 < 8; i2++) {
      const float* q = xp + i2 * (H_ * W_);
      float s2 = Wv.x * q[I.x] + Wv.y * q[I.y] + Wv.z * q[I.z] + Wv.w * q[I.w];
      r[i2] = (short)f2bu(s2);
    }
    *(short8*)&Spk[(((size_t)pt * NKS_ + ks) * 64 + qd * 16 + lm) * 8] = r;
  }
}

// -------------------------------------- K2b: MFMA GEMM + fused channel stats
// Block = 256 thr (4 waves) = 256 couts x 32 px. Wave = 64 couts (4 m-tiles)
// x 2 n-tiles, 8 MFMA/k-step. B prefetch ring depth 4 (covers L3 latency),
// A double-buffered (L2-hot).
__global__ __launch_bounds__(256) void k_gemm(const unsigned short* __restrict__ Apk,
                                              const unsigned short* __restrict__ Spk,
                                              const float* __restrict__ db,
                                              float* __restrict__ outp,
                                              float* __restrict__ accum) {
  const int tid = threadIdx.x;
  const int wv = tid >> 6;
  const int ln = tid & 63;
  const int lm = ln & 15;
  const int qd = ln >> 4;
  const int pt0 = blockIdx.x * 2;          // two 16-px tiles
  const int cbase = wv * 64;

  floatx4 acc[4][2];
#pragma unroll
  for (int mt = 0; mt < 4; mt++)
#pragma unroll
    for (int nt = 0; nt < 2; nt++) acc[mt][nt] = (floatx4){0.f, 0.f, 0.f, 0.f};

  const unsigned short* ap0 = Apk + (cbase + lm) * 32 + qd * 8;        // +ks*8192 +mt*512
  const unsigned short* bp0 = Spk + (size_t)pt0 * NKS_ * 512 + ln * 8; // +ks*512 +nt*NKS_*512

  short8 A[2][4], Bv[4][2];
#pragma unroll
  for (int mt = 0; mt < 4; mt++) A[0][mt] = *(const short8*)(ap0 + mt * 512);
#pragma unroll
  for (int st = 0; st < 3; st++)
#pragma unroll
    for (int nt = 0; nt < 2; nt++)
      Bv[st][nt] = *(const short8*)(bp0 + st * 512 + (size_t)nt * NKS_ * 512);

#pragma unroll 4
  for (int ks = 0; ks < NKS_; ks++) {
    const int ac = ks & 1, bc = ks & 3;
    if (ks + 1 < NKS_) {
      const unsigned short* ap = ap0 + (ks + 1) * 8192;
#pragma unroll
      for (int mt = 0; mt < 4; mt++) A[ac ^ 1][mt] = *(const short8*)(ap + mt * 512);
    }
    if (ks + 3 < NKS_) {
      const int bn = (ks + 3) & 3;
#pragma unroll
      for (int nt = 0; nt < 2; nt++)
        Bv[bn][nt] = *(const short8*)(bp0 + (ks + 3) * 512 + (size_t)nt * NKS_ * 512);
    }
#pragma unroll
    for (int mt = 0; mt < 4; mt++)
#pragma unroll
      for (int nt = 0; nt < 2; nt++)
        acc[mt][nt] = __builtin_amdgcn_mfma_f32_16x16x32_bf16(A[ac][mt], Bv[bc][nt],
                                                              acc[mt][nt], 0, 0, 0);
  }

  // Epilogue: bias + store + per-channel stats (layout verified r3-r5).
  float s1[16], s2[16];
#pragma unroll
  for (int i = 0; i < 16; i++) { s1[i] = 0.f; s2[i] = 0.f; }

#pragma unroll
  for (int nt = 0; nt < 2; nt++) {
    int p = (pt0 + nt) * 16 + lm;
    int bb = p / 1600, rem = p % 1600;
    float* ob = outp + (size_t)bb * COUT_ * 1600 + rem;
#pragma unroll
    for (int mt = 0; mt < 4; mt++) {
#pragma unroll
      for (int r = 0; r < 4; r++) {
        const int c = cbase + mt * 16 + qd * 4 + r;
        float v = acc[mt][nt][r] + db[c];
        ob[(size_t)c * 1600] = v;
        s1[mt * 4 + r] += v;
        s2[mt * 4 + r] += v * v;
      }
    }
  }
#pragma unroll
  for (int d = 1; d < 16; d <<= 1) {
#pragma unroll
    for (int i = 0; i < 16; i++) {
      s1[i] += __shfl_xor(s1[i], d, 64);
      s2[i] += __shfl_xor(s2[i], d, 64);
    }
  }
  if (lm == 0) {
#pragma unroll
    for (int i = 0; i < 16; i++) {
      int c = cbase + (i >> 2) * 16 + qd * 4 + (i & 3);
      atomicAdd(&accum[c], s1[i]);
      atomicAdd(&accum[COUT_ + c], s2[i]);
    }
  }
}

// --------------------------------------------------- K3: BN + SiLU, in place
__global__ __launch_bounds__(256) void k_bn(float* __restrict__ io,
                                            const float* __restrict__ accum,
                                            const float* __restrict__ gamma,
                                            const float* __restrict__ beta) {
  const int t = blockIdx.x * 256 + threadIdx.x;
  const int i0 = t * 4;
  const int c = (i0 / (HO_ * WO_)) % COUT_;
  const float mean = accum[c] * (1.f / NPIX_);
  const float var  = accum[COUT_ + c] * (1.f / NPIX_) - mean * mean;
  const float inv  = rsqrtf(var + 1e-5f);
  const float g  = gamma[c] * inv;
  const float be = beta[c] - mean * g;
  float4 r = *(const float4*)(io + i0);
  float v[4] = {r.x, r.y, r.z, r.w};
#pragma unroll
  for (int q = 0; q < 4; q++) {
    float u = v[q] * g + be;
    v[q] = u / (1.f + expf(-u));
  }
  *(float4*)(io + i0) = make_float4(v[0], v[1], v[2], v[3]);
}

// ----------------------------------------------------------------- launcher
extern "C" void kernel_launch(void* const* d_in, const int* in_sizes, int n_in,
                              void* d_out, int out_size, void* d_ws, size_t ws_size,
                              hipStream_t stream) {
  const float* x     = (const float*)d_in[0];
  const float* ow    = (const float*)d_in[1];
  const float* ob    = (const float*)d_in[2];
  const float* dw    = (const float*)d_in[3];
  const float* db    = (const float*)d_in[4];
  const float* gamma = (const float*)d_in[5];
  const float* beta  = (const float*)d_in[6];
  float* out = (float*)d_out;

  float* off   = (float*)d_ws;                                 // 460800 f
  float* accum = off + B_ * 18 * HO_ * WO_;                    // 512 f
  unsigned short* Apk = (unsigned short*)(accum + 2 * COUT_);  // 294912 us
  unsigned short* Spk = Apk + (size_t)SK_ * COUT_;             // 29491200 us
  unsigned short* xcl = Spk + (size_t)NPIX_ * SK_;             // 13107200 us
  const size_t need = (size_t)((char*)(xcl + (size_t)B_ * H_ * W_ * CIN_) - (char*)d_ws);

  hipMemsetAsync(accum, 0, 2 * COUT_ * sizeof(float), stream);
  k_offsets<<<B_ * HO_, 256, 0, stream>>>(x, ow, ob, off);
  k_pack<<<SK_, 256, 0, stream>>>(dw, Apk);
  if (ws_size >= need) {
    k_cl<<<B_ * H_, 256, 0, stream>>>(x, xcl);
    k_sample_cl<<<B_ * KK_ * 20, 256, 0, stream>>>(xcl, off, Spk);
  } else {
    k_sample<<<B_ * KK_ * 20, 256, 0, stream>>>(x, off, Spk);
  }
  k_gemm<<<NPIX_ / 32, 256, 0, stream>>>(Apk, Spk, db, out, accum);
  k_bn<<<(NPIX_ * COUT_ / 4 + 255) / 256, 256, 0, stream>>>(
      out, accum, gamma, beta);
}

// Round 7
// 266.822 us; speedup vs baseline: 1.7500x; 1.0114x over previous
//
#include <hip/hip_runtime.h>
#include <hip/hip_bf16.h>

#define B_    16
#define CIN_  128
#define COUT_ 256
#define H_    80
#define W_    80
#define HO_   40
#define WO_   40
#define KK_   9
#define SK_   1152      // CIN_*KK_
#define NPIX_ 25600     // B_*HO_*WO_
#define NKS_  36        // K / 32

typedef __attribute__((ext_vector_type(8))) short short8;
typedef __attribute__((ext_vector_type(4))) float floatx4;

__device__ __forceinline__ unsigned short f2bu(float v) {
  __hip_bfloat16 h = __float2bfloat16(v);
  return *reinterpret_cast<unsigned short*>(&h);
}
__device__ __forceinline__ float bu2f(unsigned short u) {
  return __uint_as_float(((unsigned)u) << 16);
}
// async global->LDS DMA, 16B per lane. LDS dest = wave-uniform base + lane*16.
__device__ __forceinline__ void gl_lds16(const unsigned short* g, unsigned short* l) {
  __builtin_amdgcn_global_load_lds(
      (const __attribute__((address_space(1))) unsigned int*)(const void*)g,
      (__attribute__((address_space(3))) unsigned int*)(void*)l, 16, 0, 0);
}

// ---------------------------------------------------------------- K1: offsets
__global__ __launch_bounds__(256) void k_offsets(const float* __restrict__ x,
                                                 const float* __restrict__ ow,
                                                 const float* __restrict__ ob,
                                                 float* __restrict__ off) {
  __shared__ float xrow[CIN_ * WO_];
  __shared__ float owl[18 * CIN_];
  __shared__ float obl[18];
  const int tid = threadIdx.x;
  const int b  = blockIdx.x / HO_;
  const int ho = blockIdx.x % HO_;
  for (int j = tid; j < CIN_ * WO_; j += 256) {
    int ci = j / WO_, wo = j - ci * WO_;
    xrow[j] = x[((b * CIN_ + ci) * H_ + 2 * ho) * W_ + 2 * wo];
  }
  for (int j = tid; j < 18 * CIN_; j += 256) owl[j] = ow[j];
  if (tid < 18) obl[tid] = ob[tid];
  __syncthreads();
  for (int i = tid; i < 18 * WO_; i += 256) {
    int o = i / WO_, wo = i - o * WO_;
    float acc = obl[o];
    const float* wr = &owl[o * CIN_];
    const float* xr = &xrow[wo];
#pragma unroll 4
    for (int ci = 0; ci < CIN_; ci++) acc += wr[ci] * xr[ci * WO_];
    off[((b * 18 + o) * HO_ + ho) * WO_ + wo] = acc;
  }
}

// ------------------------------------------------- KT: pack weights for MFMA
// (verified round 3) K reordered as s' = kk*128 + ci. Apk[ks][m][quad][j] bf16.
__global__ __launch_bounds__(256) void k_pack(const float* __restrict__ dw,
                                              unsigned short* __restrict__ Apk) {
  int t = blockIdx.x * 256 + threadIdx.x;   // 0..294911
  int j  = t & 7;
  int qd = (t >> 3) & 3;
  int m  = (t >> 5) & 255;
  int ks = t >> 13;
  int k  = ks * 32 + qd * 8 + j;
  int kk = k >> 7, ci = k & 127;
  Apk[t] = f2bu(dw[m * SK_ + ci * KK_ + kk]);
}

// ---------------------------------------- KC: x -> channels-last bf16 (xcl)
__global__ __launch_bounds__(256) void k_cl(const float* __restrict__ x,
                                            unsigned short* __restrict__ xcl) {
  __shared__ float ts[CIN_][W_ + 1];
  const int tid = threadIdx.x;
  const int b = blockIdx.x / H_;
  const int y = blockIdx.x % H_;
  for (int j = tid; j < CIN_ * 20; j += 256) {
    int ci = j / 20, xq = j % 20;
    float4 v = *(const float4*)&x[(((size_t)b * CIN_ + ci) * H_ + y) * W_ + xq * 4];
    ts[ci][xq * 4 + 0] = v.x;
    ts[ci][xq * 4 + 1] = v.y;
    ts[ci][xq * 4 + 2] = v.z;
    ts[ci][xq * 4 + 3] = v.w;
  }
  __syncthreads();
  unsigned short* op = xcl + ((size_t)b * H_ * W_ + (size_t)y * W_) * CIN_;
  for (int j = tid; j < W_ * 32; j += 256) {
    int xx = j >> 5, cg = j & 31;
    unsigned short b0 = f2bu(ts[cg * 4 + 0][xx]);
    unsigned short b1 = f2bu(ts[cg * 4 + 1][xx]);
    unsigned short b2 = f2bu(ts[cg * 4 + 2][xx]);
    unsigned short b3 = f2bu(ts[cg * 4 + 3][xx]);
    uint2 pk = make_uint2((unsigned)b0 | ((unsigned)b1 << 16),
                          (unsigned)b2 | ((unsigned)b3 << 16));
    *(uint2*)(op + (size_t)xx * CIN_ + cg * 4) = pk;
  }
}

// ------------------------------------------ K2a: sampling from channels-last
// (verified round 6) XCD-swizzled by b; coalesced 16B corner loads.
__global__ __launch_bounds__(256) void k_sample_cl(const unsigned short* __restrict__ xcl,
                                                   const float* __restrict__ off,
                                                   unsigned short* __restrict__ Spk) {
  __shared__ __align__(16) int   pidx[80 * 4];
  __shared__ __align__(16) float pw[80 * 4];
  const int tid = threadIdx.x;
  const int j0   = blockIdx.x;         // 0..2879
  const int xcd  = j0 & 7;
  const int s    = j0 >> 3;
  const int b_hi = s / 180;
  const int t0   = s % 180;
  const int g    = t0 / 9;
  const int kk   = t0 % 9;
  const int b    = b_hi * 8 + xcd;
  const int ho0  = g * 2;

  if (tid < 80) {
    int hop = tid / 40, px = tid % 40;
    int ho = ho0 + hop;
    float dy = off[((b * 18 + 2 * kk) * HO_ + ho) * WO_ + px];
    float dx = off[((b * 18 + 2 * kk + 1) * HO_ + ho) * WO_ + px];
    float py  = (float)(2 * ho - 1 + (kk / 3)) + dy;
    float pxf = (float)(2 * px - 1 + (kk % 3)) + dx;
    float y0f = floorf(py), x0f = floorf(pxf);
    float wy1 = py - y0f, wx1 = pxf - x0f;
    float wy0 = 1.f - wy1, wx0 = 1.f - wx1;
    int y0 = (int)y0f, x0 = (int)x0f;
    int y1 = y0 + 1, x1 = x0 + 1;
    bool vy0 = (y0 >= 0) && (y0 < H_);
    bool vy1 = (y1 >= 0) && (y1 < H_);
    bool vx0 = (x0 >= 0) && (x0 < W_);
    bool vx1 = (x1 >= 0) && (x1 < W_);
    int y0c = min(max(y0, 0), H_ - 1), y1c = min(max(y1, 0), H_ - 1);
    int x0c = min(max(x0, 0), W_ - 1), x1c = min(max(x1, 0), W_ - 1);
    pidx[tid * 4 + 0] = (y0c * W_ + x0c) << 7;  pw[tid * 4 + 0] = (vy0 && vx0) ? wy0 * wx0 : 0.f;
    pidx[tid * 4 + 1] = (y0c * W_ + x1c) << 7;  pw[tid * 4 + 1] = (vy0 && vx1) ? wy0 * wx1 : 0.f;
    pidx[tid * 4 + 2] = (y1c * W_ + x0c) << 7;  pw[tid * 4 + 2] = (vy1 && vx0) ? wy1 * wx0 : 0.f;
    pidx[tid * 4 + 3] = (y1c * W_ + x1c) << 7;  pw[tid * 4 + 3] = (vy1 && vx1) ? wy1 * wx1 : 0.f;
  }
  __syncthreads();

  const unsigned short* xb = xcl + (size_t)b * (H_ * W_ * CIN_);
#pragma unroll
  for (int it = 0; it < 5; it++) {
    int i = it * 256 + tid;            // (pxh, oct), oct fastest
    int oct = i & 15;
    int pxh = i >> 4;                  // 0..79
    int4   I  = *(const int4*)&pidx[pxh * 4];
    float4 Wv = *(const float4*)&pw[pxh * 4];
    short8 c00 = *(const short8*)(xb + I.x + oct * 8);
    short8 c01 = *(const short8*)(xb + I.y + oct * 8);
    short8 c10 = *(const short8*)(xb + I.z + oct * 8);
    short8 c11 = *(const short8*)(xb + I.w + oct * 8);
    short8 r;
#pragma unroll
    for (int i2 = 0; i2 < 8; i2++) {
      float v = Wv.x * bu2f((unsigned short)c00[i2]) +
                Wv.y * bu2f((unsigned short)c01[i2]) +
                Wv.z * bu2f((unsigned short)c10[i2]) +
                Wv.w * bu2f((unsigned short)c11[i2]);
      r[i2] = (short)f2bu(v);
    }
    int p  = b * 1600 + (ho0 + (pxh / 40)) * 40 + (pxh % 40);
    int pt = p >> 4, lm = p & 15;
    int ks = kk * 4 + (oct >> 2);
    int qd = oct & 3;
    *(short8*)&Spk[(((size_t)pt * NKS_ + ks) * 64 + qd * 16 + lm) * 8] = r;
  }
}

// ------------------------- K2b: MFMA GEMM, LDS double-buffer (m97 structure)
// Block = 128 couts x 64 px, 256 thr (2x2 waves, each 64 couts x 32 px).
// K-loop: 36 steps of 32; next k-slab staged via global_load_lds (async DMA,
// cannot be sunk by compiler) into buf^1 while MFMA consumes buf.
// blockIdx swizzled so b == (bid&7) matches k_sample's writer XCD -> Spk
// reads hit the local L2.
__global__ __launch_bounds__(256) void k_gemm(const unsigned short* __restrict__ Apk,
                                              const unsigned short* __restrict__ Spk,
                                              const float* __restrict__ db,
                                              float* __restrict__ outp,
                                              float* __restrict__ accum) {
  __shared__ __align__(16) unsigned short a_sh[2][4096];  // 16 KB: 128 couts x 32k
  __shared__ __align__(16) unsigned short b_sh[2][2048];  //  8 KB: 4 pt x frag-order

  const int tid = threadIdx.x;
  const int wv = tid >> 6;
  const int ln = tid & 63;
  const int lm = ln & 15;
  const int qd = ln >> 4;
  const int wm = wv >> 1;              // cout-half within block's 128
  const int wn = wv & 1;               // px-half (2 pt tiles)

  // swizzle: xcd = bid&7 must equal b&7
  const int bid  = blockIdx.x;         // 0..799
  const int xcd  = bid & 7;
  const int t    = bid >> 3;           // 0..99
  const int b_hi = t / 50;
  const int idx  = t % 50;
  const int b    = b_hi * 8 + xcd;
  const int g4   = b * 25 + (idx >> 1);   // 64-px group, 0..399
  const int chalf = idx & 1;
  const int pt0  = g4 * 4;

  // staging pointers (per k-step ks):
  //   A: Apk + ks*8192 + chalf*4096  (4096 ushorts = 8 KB, 2 rounds of 4 KB)
  //   B: Spk + ((pt0+wv)*36 + ks)*512 (512 ushorts per wave)
  const unsigned short* agbase = Apk + chalf * 4096 + tid * 8;
  const unsigned short* bgbase = Spk + ((size_t)(pt0 + wv) * NKS_) * 512 + ln * 8;
  unsigned short* a_l0 = &a_sh[0][0] + (tid >> 6) * 512 + ((tid & 63) ? 0 : 0); // wave-uniform part below
  // wave-uniform LDS bases (lane offset added by HW):
  // A round r: a_sh[buf] + r*2048 + wv*512 ; B: b_sh[buf] + wv*512

  floatx4 acc[4][2];
#pragma unroll
  for (int mt = 0; mt < 4; mt++)
#pragma unroll
    for (int nt = 0; nt < 2; nt++) acc[mt][nt] = (floatx4){0.f, 0.f, 0.f, 0.f};

  // prologue: stage ks=0 into buf 0
  gl_lds16(agbase + 0 * 8192,        &a_sh[0][0] + (wv)*512);          // r0
  gl_lds16(agbase + 0 * 8192 + 2048, &a_sh[0][2048] + (wv)*512);       // r1
  gl_lds16(bgbase + 0 * 512,         &b_sh[0][0] + wv * 512);
  __syncthreads();

  for (int ks = 0; ks < NKS_; ks++) {
    const int buf = ks & 1, nb = buf ^ 1;
    if (ks + 1 < NKS_) {
      gl_lds16(agbase + (ks + 1) * 8192,        &a_sh[nb][0] + wv * 512);
      gl_lds16(agbase + (ks + 1) * 8192 + 2048, &a_sh[nb][2048] + wv * 512);
      gl_lds16(bgbase + (size_t)(ks + 1) * 512, &b_sh[nb][0] + wv * 512);
    }
    const unsigned short* al = &a_sh[buf][0] + (wm * 64 + lm) * 32 + qd * 8;
    const unsigned short* bl = &b_sh[buf][0] + wn * 1024 + ln * 8;
    short8 a0 = *(const short8*)(al + 0 * 16 * 32);
    short8 a1 = *(const short8*)(al + 1 * 16 * 32);
    short8 a2 = *(const short8*)(al + 2 * 16 * 32);
    short8 a3 = *(const short8*)(al + 3 * 16 * 32);
    short8 b0 = *(const short8*)(bl);
    short8 b1 = *(const short8*)(bl + 512);
    acc[0][0] = __builtin_amdgcn_mfma_f32_16x16x32_bf16(a0, b0, acc[0][0], 0, 0, 0);
    acc[0][1] = __builtin_amdgcn_mfma_f32_16x16x32_bf16(a0, b1, acc[0][1], 0, 0, 0);
    acc[1][0] = __builtin_amdgcn_mfma_f32_16x16x32_bf16(a1, b0, acc[1][0], 0, 0, 0);
    acc[1][1] = __builtin_amdgcn_mfma_f32_16x16x32_bf16(a1, b1, acc[1][1], 0, 0, 0);
    acc[2][0] = __builtin_amdgcn_mfma_f32_16x16x32_bf16(a2, b0, acc[2][0], 0, 0, 0);
    acc[2][1] = __builtin_amdgcn_mfma_f32_16x16x32_bf16(a2, b1, acc[2][1], 0, 0, 0);
    acc[3][0] = __builtin_amdgcn_mfma_f32_16x16x32_bf16(a3, b0, acc[3][0], 0, 0, 0);
    acc[3][1] = __builtin_amdgcn_mfma_f32_16x16x32_bf16(a3, b1, acc[3][1], 0, 0, 0);
    __syncthreads();   // drains DMA (vmcnt) + protects buf reuse
  }

  // Epilogue: bias + store + per-channel stats (layout verified r3-r6).
  float s1[16], s2[16];
#pragma unroll
  for (int i = 0; i < 16; i++) { s1[i] = 0.f; s2[i] = 0.f; }

#pragma unroll
  for (int nt = 0; nt < 2; nt++) {
    int p = (pt0 + wn * 2 + nt) * 16 + lm;
    int bb = p / 1600, rem = p % 1600;
    float* ob = outp + (size_t)bb * COUT_ * 1600 + rem;
#pragma unroll
    for (int mt = 0; mt < 4; mt++) {
#pragma unroll
      for (int r = 0; r < 4; r++) {
        const int c = chalf * 128 + wm * 64 + mt * 16 + qd * 4 + r;
        float v = acc[mt][nt][r] + db[c];
        ob[(size_t)c * 1600] = v;
        s1[mt * 4 + r] += v;
        s2[mt * 4 + r] += v * v;
      }
    }
  }
#pragma unroll
  for (int d = 1; d < 16; d <<= 1) {
#pragma unroll
    for (int i = 0; i < 16; i++) {
      s1[i] += __shfl_xor(s1[i], d, 64);
      s2[i] += __shfl_xor(s2[i], d, 64);
    }
  }
  if (lm == 0) {
#pragma unroll
    for (int i = 0; i < 16; i++) {
      int c = chalf * 128 + wm * 64 + (i >> 2) * 16 + qd * 4 + (i & 3);
      atomicAdd(&accum[c], s1[i]);
      atomicAdd(&accum[COUT_ + c], s2[i]);
    }
  }
  (void)a_l0;
}

// --------------------------------------------------- K3: BN + SiLU, in place
__global__ __launch_bounds__(256) void k_bn(float* __restrict__ io,
                                            const float* __restrict__ accum,
                                            const float* __restrict__ gamma,
                                            const float* __restrict__ beta) {
  const int t = blockIdx.x * 256 + threadIdx.x;
  const int i0 = t * 4;
  const int c = (i0 / (HO_ * WO_)) % COUT_;
  const float mean = accum[c] * (1.f / NPIX_);
  const float var  = accum[COUT_ + c] * (1.f / NPIX_) - mean * mean;
  const float inv  = rsqrtf(var + 1e-5f);
  const float g  = gamma[c] * inv;
  const float be = beta[c] - mean * g;
  float4 r = *(const float4*)(io + i0);
  float v[4] = {r.x, r.y, r.z, r.w};
#pragma unroll
  for (int q = 0; q < 4; q++) {
    float u = v[q] * g + be;
    v[q] = u / (1.f + expf(-u));
  }
  *(float4*)(io + i0) = make_float4(v[0], v[1], v[2], v[3]);
}

// ----------------------------------------------------------------- launcher
extern "C" void kernel_launch(void* const* d_in, const int* in_sizes, int n_in,
                              void* d_out, int out_size, void* d_ws, size_t ws_size,
                              hipStream_t stream) {
  const float* x     = (const float*)d_in[0];
  const float* ow    = (const float*)d_in[1];
  const float* ob    = (const float*)d_in[2];
  const float* dw    = (const float*)d_in[3];
  const float* db    = (const float*)d_in[4];
  const float* gamma = (const float*)d_in[5];
  const float* beta  = (const float*)d_in[6];
  float* out = (float*)d_out;

  float* off   = (float*)d_ws;                                 // 460800 f
  float* accum = off + B_ * 18 * HO_ * WO_;                    // 512 f
  unsigned short* Apk = (unsigned short*)(accum + 2 * COUT_);  // 294912 us
  unsigned short* Spk = Apk + (size_t)SK_ * COUT_;             // 29491200 us
  unsigned short* xcl = Spk + (size_t)NPIX_ * SK_;             // 13107200 us

  hipMemsetAsync(accum, 0, 2 * COUT_ * sizeof(float), stream);
  k_offsets<<<B_ * HO_, 256, 0, stream>>>(x, ow, ob, off);
  k_pack<<<SK_, 256, 0, stream>>>(dw, Apk);
  k_cl<<<B_ * H_, 256, 0, stream>>>(x, xcl);
  k_sample_cl<<<B_ * KK_ * 20, 256, 0, stream>>>(xcl, off, Spk);
  k_gemm<<<800, 256, 0, stream>>>(Apk, Spk, db, out, accum);
  k_bn<<<(NPIX_ * COUT_ / 4 + 255) / 256, 256, 0, stream>>>(
      out, accum, gamma, beta);
}

// Round 8
// 260.260 us; speedup vs baseline: 1.7941x; 1.0252x over previous
//
#include <hip/hip_runtime.h>
#include <hip/hip_bf16.h>

#define B_    16
#define CIN_  128
#define COUT_ 256
#define H_    80
#define W_    80
#define HO_   40
#define WO_   40
#define KK_   9
#define SK_   1152      // CIN_*KK_
#define NPIX_ 25600     // B_*HO_*WO_
#define NKS_  36        // K / 32

typedef __attribute__((ext_vector_type(8))) short short8;
typedef __attribute__((ext_vector_type(4))) float floatx4;

__device__ __forceinline__ unsigned short f2bu(float v) {
  __hip_bfloat16 h = __float2bfloat16(v);
  return *reinterpret_cast<unsigned short*>(&h);
}
__device__ __forceinline__ float bu2f(unsigned short u) {
  return __uint_as_float(((unsigned)u) << 16);
}
// async global->LDS DMA, 16B per lane. LDS dest = wave-uniform base + lane*16.
__device__ __forceinline__ void gl_lds16(const unsigned short* g, unsigned short* l) {
  __builtin_amdgcn_global_load_lds(
      (const __attribute__((address_space(1))) unsigned int*)(const void*)g,
      (__attribute__((address_space(3))) unsigned int*)(void*)l, 16, 0, 0);
}

// ---------------------------------------------------------------- K1: offsets
__global__ __launch_bounds__(256) void k_offsets(const float* __restrict__ x,
                                                 const float* __restrict__ ow,
                                                 const float* __restrict__ ob,
                                                 float* __restrict__ off) {
  __shared__ float xrow[CIN_ * WO_];
  __shared__ float owl[18 * CIN_];
  __shared__ float obl[18];
  const int tid = threadIdx.x;
  const int b  = blockIdx.x / HO_;
  const int ho = blockIdx.x % HO_;
  for (int j = tid; j < CIN_ * WO_; j += 256) {
    int ci = j / WO_, wo = j - ci * WO_;
    xrow[j] = x[((b * CIN_ + ci) * H_ + 2 * ho) * W_ + 2 * wo];
  }
  for (int j = tid; j < 18 * CIN_; j += 256) owl[j] = ow[j];
  if (tid < 18) obl[tid] = ob[tid];
  __syncthreads();
  for (int i = tid; i < 18 * WO_; i += 256) {
    int o = i / WO_, wo = i - o * WO_;
    float acc = obl[o];
    const float* wr = &owl[o * CIN_];
    const float* xr = &xrow[wo];
#pragma unroll 4
    for (int ci = 0; ci < CIN_; ci++) acc += wr[ci] * xr[ci * WO_];
    off[((b * 18 + o) * HO_ + ho) * WO_ + wo] = acc;
  }
}

// ------------------------------------------------- KT: pack weights for MFMA
// (verified round 3) K reordered as s' = kk*128 + ci. Apk[ks][m][quad][j] bf16.
__global__ __launch_bounds__(256) void k_pack(const float* __restrict__ dw,
                                              unsigned short* __restrict__ Apk) {
  int t = blockIdx.x * 256 + threadIdx.x;   // 0..294911
  int j  = t & 7;
  int qd = (t >> 3) & 3;
  int m  = (t >> 5) & 255;
  int ks = t >> 13;
  int k  = ks * 32 + qd * 8 + j;
  int kk = k >> 7, ci = k & 127;
  Apk[t] = f2bu(dw[m * SK_ + ci * KK_ + kk]);
}

// ---------------------------------------- KC: x -> channels-last bf16 (xcl)
__global__ __launch_bounds__(256) void k_cl(const float* __restrict__ x,
                                            unsigned short* __restrict__ xcl) {
  __shared__ float ts[CIN_][W_ + 1];
  const int tid = threadIdx.x;
  const int b = blockIdx.x / H_;
  const int y = blockIdx.x % H_;
  for (int j = tid; j < CIN_ * 20; j += 256) {
    int ci = j / 20, xq = j % 20;
    float4 v = *(const float4*)&x[(((size_t)b * CIN_ + ci) * H_ + y) * W_ + xq * 4];
    ts[ci][xq * 4 + 0] = v.x;
    ts[ci][xq * 4 + 1] = v.y;
    ts[ci][xq * 4 + 2] = v.z;
    ts[ci][xq * 4 + 3] = v.w;
  }
  __syncthreads();
  unsigned short* op = xcl + ((size_t)b * H_ * W_ + (size_t)y * W_) * CIN_;
  for (int j = tid; j < W_ * 32; j += 256) {
    int xx = j >> 5, cg = j & 31;
    unsigned short b0 = f2bu(ts[cg * 4 + 0][xx]);
    unsigned short b1 = f2bu(ts[cg * 4 + 1][xx]);
    unsigned short b2 = f2bu(ts[cg * 4 + 2][xx]);
    unsigned short b3 = f2bu(ts[cg * 4 + 3][xx]);
    uint2 pk = make_uint2((unsigned)b0 | ((unsigned)b1 << 16),
                          (unsigned)b2 | ((unsigned)b3 << 16));
    *(uint2*)(op + (size_t)xx * CIN_ + cg * 4) = pk;
  }
}

// ------------------------------------------ K2a: sampling from channels-last
// (verified round 6) XCD-swizzled by b; coalesced 16B corner loads.
__global__ __launch_bounds__(256) void k_sample_cl(const unsigned short* __restrict__ xcl,
                                                   const float* __restrict__ off,
                                                   unsigned short* __restrict__ Spk) {
  __shared__ __align__(16) int   pidx[80 * 4];
  __shared__ __align__(16) float pw[80 * 4];
  const int tid = threadIdx.x;
  const int j0   = blockIdx.x;         // 0..2879
  const int xcd  = j0 & 7;
  const int s    = j0 >> 3;
  const int b_hi = s / 180;
  const int t0   = s % 180;
  const int g    = t0 / 9;
  const int kk   = t0 % 9;
  const int b    = b_hi * 8 + xcd;
  const int ho0  = g * 2;

  if (tid < 80) {
    int hop = tid / 40, px = tid % 40;
    int ho = ho0 + hop;
    float dy = off[((b * 18 + 2 * kk) * HO_ + ho) * WO_ + px];
    float dx = off[((b * 18 + 2 * kk + 1) * HO_ + ho) * WO_ + px];
    float py  = (float)(2 * ho - 1 + (kk / 3)) + dy;
    float pxf = (float)(2 * px - 1 + (kk % 3)) + dx;
    float y0f = floorf(py), x0f = floorf(pxf);
    float wy1 = py - y0f, wx1 = pxf - x0f;
    float wy0 = 1.f - wy1, wx0 = 1.f - wx1;
    int y0 = (int)y0f, x0 = (int)x0f;
    int y1 = y0 + 1, x1 = x0 + 1;
    bool vy0 = (y0 >= 0) && (y0 < H_);
    bool vy1 = (y1 >= 0) && (y1 < H_);
    bool vx0 = (x0 >= 0) && (x0 < W_);
    bool vx1 = (x1 >= 0) && (x1 < W_);
    int y0c = min(max(y0, 0), H_ - 1), y1c = min(max(y1, 0), H_ - 1);
    int x0c = min(max(x0, 0), W_ - 1), x1c = min(max(x1, 0), W_ - 1);
    pidx[tid * 4 + 0] = (y0c * W_ + x0c) << 7;  pw[tid * 4 + 0] = (vy0 && vx0) ? wy0 * wx0 : 0.f;
    pidx[tid * 4 + 1] = (y0c * W_ + x1c) << 7;  pw[tid * 4 + 1] = (vy0 && vx1) ? wy0 * wx1 : 0.f;
    pidx[tid * 4 + 2] = (y1c * W_ + x0c) << 7;  pw[tid * 4 + 2] = (vy1 && vx0) ? wy1 * wx0 : 0.f;
    pidx[tid * 4 + 3] = (y1c * W_ + x1c) << 7;  pw[tid * 4 + 3] = (vy1 && vx1) ? wy1 * wx1 : 0.f;
  }
  __syncthreads();

  const unsigned short* xb = xcl + (size_t)b * (H_ * W_ * CIN_);
#pragma unroll
  for (int it = 0; it < 5; it++) {
    int i = it * 256 + tid;            // (pxh, oct), oct fastest
    int oct = i & 15;
    int pxh = i >> 4;                  // 0..79
    int4   I  = *(const int4*)&pidx[pxh * 4];
    float4 Wv = *(const float4*)&pw[pxh * 4];
    short8 c00 = *(const short8*)(xb + I.x + oct * 8);
    short8 c01 = *(const short8*)(xb + I.y + oct * 8);
    short8 c10 = *(const short8*)(xb + I.z + oct * 8);
    short8 c11 = *(const short8*)(xb + I.w + oct * 8);
    short8 r;
#pragma unroll
    for (int i2 = 0; i2 < 8; i2++) {
      float v = Wv.x * bu2f((unsigned short)c00[i2]) +
                Wv.y * bu2f((unsigned short)c01[i2]) +
                Wv.z * bu2f((unsigned short)c10[i2]) +
                Wv.w * bu2f((unsigned short)c11[i2]);
      r[i2] = (short)f2bu(v);
    }
    int p  = b * 1600 + (ho0 + (pxh / 40)) * 40 + (pxh % 40);
    int pt = p >> 4, lm = p & 15;
    int ks = kk * 4 + (oct >> 2);
    int qd = oct & 3;
    *(short8*)&Spk[(((size_t)pt * NKS_ + ks) * 64 + qd * 16 + lm) * 8] = r;
  }
}

// ---------------- K2b: MFMA GEMM, LDS double-buffer, K split in 2 (grid 1600)
// Block = 128 couts x 64 px x half-K (18 steps). 4 waves (2x2), each wave
// 64 couts x 32 px, 8 MFMA/step. Partial C accumulated into zeroed d_out via
// fp32 atomics (bias dropped: per-channel bias cancels exactly through BN).
// Doubling the grid doubles independent barrier-groups per CU — the r7
// counter evidence showed residency, not loop mechanics, was the limiter.
__global__ __launch_bounds__(256) void k_gemm(const unsigned short* __restrict__ Apk,
                                              const unsigned short* __restrict__ Spk,
                                              float* __restrict__ outp) {
  __shared__ __align__(16) unsigned short a_sh[2][4096];  // 16 KB
  __shared__ __align__(16) unsigned short b_sh[2][2048];  //  8 KB

  const int tid = threadIdx.x;
  const int wv = tid >> 6;
  const int ln = tid & 63;
  const int lm = ln & 15;
  const int qd = ln >> 4;
  const int wm = wv >> 1;              // cout-half within block's 128
  const int wn = wv & 1;               // px-half (2 pt tiles)

  const int bid    = blockIdx.x;       // 0..1599
  const int g4     = bid >> 2;         // 0..399 (64-px group)
  const int chalf  = (bid >> 1) & 1;   // cout half
  const int ksplit = bid & 1;          // K half
  const int pt0 = g4 * 4;
  const int ks0 = ksplit * 18;

  const unsigned short* agbase = Apk + (size_t)ks0 * 8192 + chalf * 4096 + tid * 8;
  const unsigned short* bgbase = Spk + ((size_t)(pt0 + wv) * NKS_ + ks0) * 512 + ln * 8;

  floatx4 acc[4][2];
#pragma unroll
  for (int mt = 0; mt < 4; mt++)
#pragma unroll
    for (int nt = 0; nt < 2; nt++) acc[mt][nt] = (floatx4){0.f, 0.f, 0.f, 0.f};

  // prologue: stage local ks=0 into buf 0
  gl_lds16(agbase,        &a_sh[0][0] + wv * 512);
  gl_lds16(agbase + 2048, &a_sh[0][2048] + wv * 512);
  gl_lds16(bgbase,        &b_sh[0][0] + wv * 512);
  __syncthreads();

  for (int ks = 0; ks < 18; ks++) {
    const int buf = ks & 1, nb = buf ^ 1;
    if (ks + 1 < 18) {
      gl_lds16(agbase + (size_t)(ks + 1) * 8192,        &a_sh[nb][0] + wv * 512);
      gl_lds16(agbase + (size_t)(ks + 1) * 8192 + 2048, &a_sh[nb][2048] + wv * 512);
      gl_lds16(bgbase + (size_t)(ks + 1) * 512,         &b_sh[nb][0] + wv * 512);
    }
    const unsigned short* al = &a_sh[buf][0] + (wm * 64 + lm) * 32 + qd * 8;
    const unsigned short* bl = &b_sh[buf][0] + wn * 1024 + ln * 8;
    short8 a0 = *(const short8*)(al + 0 * 512);
    short8 a1 = *(const short8*)(al + 1 * 512);
    short8 a2 = *(const short8*)(al + 2 * 512);
    short8 a3 = *(const short8*)(al + 3 * 512);
    short8 b0 = *(const short8*)(bl);
    short8 b1 = *(const short8*)(bl + 512);
    acc[0][0] = __builtin_amdgcn_mfma_f32_16x16x32_bf16(a0, b0, acc[0][0], 0, 0, 0);
    acc[0][1] = __builtin_amdgcn_mfma_f32_16x16x32_bf16(a0, b1, acc[0][1], 0, 0, 0);
    acc[1][0] = __builtin_amdgcn_mfma_f32_16x16x32_bf16(a1, b0, acc[1][0], 0, 0, 0);
    acc[1][1] = __builtin_amdgcn_mfma_f32_16x16x32_bf16(a1, b1, acc[1][1], 0, 0, 0);
    acc[2][0] = __builtin_amdgcn_mfma_f32_16x16x32_bf16(a2, b0, acc[2][0], 0, 0, 0);
    acc[2][1] = __builtin_amdgcn_mfma_f32_16x16x32_bf16(a2, b1, acc[2][1], 0, 0, 0);
    acc[3][0] = __builtin_amdgcn_mfma_f32_16x16x32_bf16(a3, b0, acc[3][0], 0, 0, 0);
    acc[3][1] = __builtin_amdgcn_mfma_f32_16x16x32_bf16(a3, b1, acc[3][1], 0, 0, 0);
    __syncthreads();
  }

  // Epilogue: atomic partial-C accumulate (layout verified r3-r7).
#pragma unroll
  for (int nt = 0; nt < 2; nt++) {
    int p = (pt0 + wn * 2 + nt) * 16 + lm;
    int bb = p / 1600, rem = p % 1600;
    float* ob = outp + (size_t)bb * COUT_ * 1600 + rem;
#pragma unroll
    for (int mt = 0; mt < 4; mt++) {
#pragma unroll
      for (int r = 0; r < 4; r++) {
        const int c = chalf * 128 + wm * 64 + mt * 16 + qd * 4 + r;
        atomicAdd(&ob[(size_t)c * 1600], acc[mt][nt][r]);
      }
    }
  }
}

// ----------------------------------------------- K2c: per-channel sum/sq-sum
// (verified round 5) One block per cout channel; no atomics.
__global__ __launch_bounds__(256) void k_stats(const float* __restrict__ io,
                                               float* __restrict__ accum) {
  const int c = blockIdx.x;
  const int tid = threadIdx.x;
  float s1 = 0.f, s2 = 0.f;
  for (int i = tid; i < NPIX_; i += 256) {
    int b = i / 1600, r = i - b * 1600;
    float v = io[((size_t)b * COUT_ + c) * 1600 + r];
    s1 += v;
    s2 += v * v;
  }
#pragma unroll
  for (int d = 1; d < 64; d <<= 1) {
    s1 += __shfl_xor(s1, d, 64);
    s2 += __shfl_xor(s2, d, 64);
  }
  __shared__ float rs[4], rq[4];
  if ((tid & 63) == 0) { rs[tid >> 6] = s1; rq[tid >> 6] = s2; }
  __syncthreads();
  if (tid == 0) {
    accum[c]         = rs[0] + rs[1] + rs[2] + rs[3];
    accum[COUT_ + c] = rq[0] + rq[1] + rq[2] + rq[3];
  }
}

// --------------------------------------------------- K3: BN + SiLU, in place
__global__ __launch_bounds__(256) void k_bn(float* __restrict__ io,
                                            const float* __restrict__ accum,
                                            const float* __restrict__ gamma,
                                            const float* __restrict__ beta) {
  const int t = blockIdx.x * 256 + threadIdx.x;
  const int i0 = t * 4;
  const int c = (i0 / (HO_ * WO_)) % COUT_;
  const float mean = accum[c] * (1.f / NPIX_);
  const float var  = accum[COUT_ + c] * (1.f / NPIX_) - mean * mean;
  const float inv  = rsqrtf(var + 1e-5f);
  const float g  = gamma[c] * inv;
  const float be = beta[c] - mean * g;
  float4 r = *(const float4*)(io + i0);
  float v[4] = {r.x, r.y, r.z, r.w};
#pragma unroll
  for (int q = 0; q < 4; q++) {
    float u = v[q] * g + be;
    v[q] = u / (1.f + expf(-u));
  }
  *(float4*)(io + i0) = make_float4(v[0], v[1], v[2], v[3]);
}

// ----------------------------------------------------------------- launcher
extern "C" void kernel_launch(void* const* d_in, const int* in_sizes, int n_in,
                              void* d_out, int out_size, void* d_ws, size_t ws_size,
                              hipStream_t stream) {
  const float* x     = (const float*)d_in[0];
  const float* ow    = (const float*)d_in[1];
  const float* ob    = (const float*)d_in[2];
  const float* dw    = (const float*)d_in[3];
  const float* gamma = (const float*)d_in[5];
  const float* beta  = (const float*)d_in[6];
  float* out = (float*)d_out;

  float* off   = (float*)d_ws;                                 // 460800 f
  float* accum = off + B_ * 18 * HO_ * WO_;                    // 512 f
  unsigned short* Apk = (unsigned short*)(accum + 2 * COUT_);  // 294912 us
  unsigned short* Spk = Apk + (size_t)SK_ * COUT_;             // 29491200 us
  unsigned short* xcl = Spk + (size_t)NPIX_ * SK_;             // 13107200 us

  hipMemsetAsync(out, 0, (size_t)NPIX_ * COUT_ * sizeof(float), stream);
  k_offsets<<<B_ * HO_, 256, 0, stream>>>(x, ow, ob, off);
  k_pack<<<SK_, 256, 0, stream>>>(dw, Apk);
  k_cl<<<B_ * H_, 256, 0, stream>>>(x, xcl);
  k_sample_cl<<<B_ * KK_ * 20, 256, 0, stream>>>(xcl, off, Spk);
  k_gemm<<<1600, 256, 0, stream>>>(Apk, Spk, out);
  k_stats<<<COUT_, 256, 0, stream>>>(out, accum);
  k_bn<<<(NPIX_ * COUT_ / 4 + 255) / 256, 256, 0, stream>>>(
      out, accum, gamma, beta);
}